// Round 1
// baseline (1877.563 us; speedup 1.0000x reference)
//
#include <hip/hip_runtime.h>
#include <hip/hip_bf16.h>
#include <math.h>

constexpr int B_ = 8, H_ = 96, W_ = 160;
constexpr int HW_ = H_ * W_;
constexpr int CF_ = 64, OC_ = 64, G_ = 8;
constexpr int CIN1 = 196;   // 64*3 + 4
constexpr int C4   = 216;   // K*K*3*G

// ---------------------------------------------------------------------------
// Generic direct 3x3 conv (pad=1), NCHW.
// Block = (32,8) = 256 threads. Each thread computes PX pixels (stacked in y)
// for OCB output channels. Input tile + weight chunk staged in LDS.
// CAT=true: virtual concat of [x0(64), x1(64), x2(64), f1(2), f2(2)].
// ---------------------------------------------------------------------------
template<int CIN, int OCB, int PX, bool RELU, bool CAT>
__global__ __launch_bounds__(256) void conv3x3_k(
    const float* __restrict__ in,
    const float* __restrict__ x1, const float* __restrict__ x2,
    const float* __restrict__ f1, const float* __restrict__ f2,
    const float* __restrict__ wgt, const float* __restrict__ bia,
    float* __restrict__ out, int nOcb, int coutTot)
{
    static_assert(OCB % 4 == 0, "OCB must be multiple of 4");
    constexpr int CC = 8;
    constexpr int TW = 32, TH = 8;
    constexpr int TPH = TH * PX;

    __shared__ __align__(16) float s_in[CC][TPH + 2][TW + 2];
    __shared__ __align__(16) float s_w[CC][9][OCB];

    const int tx = threadIdx.x, ty = threadIdx.y;
    const int tid = ty * TW + tx;
    const int x0 = blockIdx.x * TW;
    const int y0 = blockIdx.y * TPH;
    const int b  = blockIdx.z / nOcb;
    const int ocb = blockIdx.z % nOcb;
    const int ocBase = ocb * OCB;

    float acc[PX][OCB];
    #pragma unroll
    for (int p = 0; p < PX; ++p)
        #pragma unroll
        for (int o = 0; o < OCB; ++o) acc[p][o] = bia[ocBase + o];

    const int nChunk = (CIN + CC - 1) / CC;
    for (int ch = 0; ch < nChunk; ++ch) {
        const int c0 = ch * CC;
        __syncthreads();
        // ---- stage input tile (zero-fill halo + channels past CIN) ----
        constexpr int IN_ELEMS = CC * (TPH + 2) * (TW + 2);
        for (int idx = tid; idx < IN_ELEMS; idx += 256) {
            int c  = idx / ((TPH + 2) * (TW + 2));
            int r  = (idx / (TW + 2)) % (TPH + 2);
            int cl = idx % (TW + 2);
            int gy = y0 + r - 1, gx = x0 + cl - 1;
            int gc = c0 + c;
            float v = 0.f;
            if (gc < CIN && gy >= 0 && gy < H_ && gx >= 0 && gx < W_) {
                if (CAT) {
                    const float* src; int scc, nc;
                    if (gc < 64)       { src = in; scc = gc;       nc = 64; }
                    else if (gc < 128) { src = x1; scc = gc - 64;  nc = 64; }
                    else if (gc < 192) { src = x2; scc = gc - 128; nc = 64; }
                    else if (gc < 194) { src = f1; scc = gc - 192; nc = 2;  }
                    else               { src = f2; scc = gc - 194; nc = 2;  }
                    v = src[((size_t)(b * nc + scc) * H_ + gy) * W_ + gx];
                } else {
                    v = in[((size_t)(b * CIN + gc) * H_ + gy) * W_ + gx];
                }
            }
            s_in[c][r][cl] = v;
        }
        // ---- stage weight chunk ----
        constexpr int W_ELEMS = CC * 9 * OCB;
        for (int idx = tid; idx < W_ELEMS; idx += 256) {
            int oc = idx / (CC * 9);
            int c  = (idx / 9) % CC;
            int t  = idx % 9;
            int gc = c0 + c;
            float v = (gc < CIN) ? wgt[((size_t)(ocBase + oc) * CIN + gc) * 9 + t] : 0.f;
            s_w[c][t][oc] = v;
        }
        __syncthreads();
        // ---- FMA inner loop ----
        #pragma unroll
        for (int c = 0; c < CC; ++c) {
            #pragma unroll
            for (int t = 0; t < 9; ++t) {
                const int di = t / 3, dj = t % 3;
                float xv[PX];
                #pragma unroll
                for (int p = 0; p < PX; ++p)
                    xv[p] = s_in[c][ty * PX + p + di][tx + dj];
                #pragma unroll
                for (int o4 = 0; o4 < OCB / 4; ++o4) {
                    float4 wv = *reinterpret_cast<const float4*>(&s_w[c][t][o4 * 4]);
                    #pragma unroll
                    for (int p = 0; p < PX; ++p) {
                        acc[p][o4 * 4 + 0] += xv[p] * wv.x;
                        acc[p][o4 * 4 + 1] += xv[p] * wv.y;
                        acc[p][o4 * 4 + 2] += xv[p] * wv.z;
                        acc[p][o4 * 4 + 3] += xv[p] * wv.w;
                    }
                }
            }
        }
    }
    // ---- store ----
    #pragma unroll
    for (int p = 0; p < PX; ++p) {
        const int gy = y0 + ty * PX + p;
        const int gx = x0 + tx;
        #pragma unroll
        for (int o = 0; o < OCB; ++o) {
            float v = acc[p][o];
            if (RELU) v = (v >= 0.f) ? v : 0.1f * v;
            out[((size_t)(b * coutTot + ocBase + o) * H_ + gy) * W_ + gx] = v;
        }
    }
}

// ---------------------------------------------------------------------------
// Fused offset/mask decode + deformable conv.
// o4: (B, 216, H, W) = [offset(144) | mask_raw(72)].
// offset channel (g*9+t)*2 + d, d=0 -> dy (+= flow ch1), d=1 -> dx (+= flow ch0).
// flow1 for groups 0..3, flow2 for 4..7. mask = sigmoid(o4[144 + g*9 + t]).
// ys = dy + h - 1 + i ; xs = dx + w - 1 + j ; bilinear, zero outside.
// out[b,oc,h,w] = bias[oc] + sum_{g,c,t} sampled * weight[oc][g*8+c][t]
// ---------------------------------------------------------------------------
__global__ __launch_bounds__(256) void deform_k(
    const float* __restrict__ x,     // B,64,H,W (current_feature_warped)
    const float* __restrict__ o4,    // B,216,H,W
    const float* __restrict__ f1,    // B,2,H,W
    const float* __restrict__ f2,    // B,2,H,W
    const float* __restrict__ wgt,   // 64,64,3,3
    const float* __restrict__ bia,   // 64
    float* __restrict__ out)         // B,64,H,W
{
    __shared__ __align__(16) float s_w[8][9][64];   // cin-in-group, tap, oc

    const int tid = threadIdx.x;
    const int p = blockIdx.x * 256 + tid;
    const int w = p % W_;
    const int h = (p / W_) % H_;
    const int b = p / HW_;

    float acc[64];
    #pragma unroll
    for (int o = 0; o < 64; ++o) acc[o] = bia[o];

    const size_t bO4 = (size_t)b * C4 * HW_;
    const size_t pix = (size_t)h * W_ + w;
    const size_t bF  = (size_t)b * 2 * HW_;

    for (int g = 0; g < G_; ++g) {
        __syncthreads();
        for (int idx = tid; idx < 8 * 9 * 64; idx += 256) {
            int oc = idx / 72;
            int c  = (idx / 9) % 8;
            int t  = idx % 9;
            s_w[c][t][oc] = wgt[((size_t)oc * 64 + g * 8 + c) * 9 + t];
        }
        __syncthreads();

        const float* fl = (g < 4) ? f1 : f2;
        const float fy = fl[bF + (size_t)1 * HW_ + pix];  // flow[:, ::-1][even] = ch1
        const float fx = fl[bF + (size_t)0 * HW_ + pix];

        #pragma unroll
        for (int t = 0; t < 9; ++t) {
            const int i = t / 3, j = t % 3;
            const int offch = (g * 9 + t) * 2;
            float dy = o4[bO4 + (size_t)offch * HW_ + pix] + fy;
            float dx = o4[bO4 + (size_t)(offch + 1) * HW_ + pix] + fx;
            float mr = o4[bO4 + (size_t)(144 + g * 9 + t) * HW_ + pix];
            float m  = 1.f / (1.f + expf(-mr));

            float ys = dy + (float)(h - 1 + i);
            float xs = dx + (float)(w - 1 + j);
            float y0f = floorf(ys), x0f = floorf(xs);
            float wy1 = ys - y0f, wx1 = xs - x0f;
            float wy0 = 1.f - wy1, wx0 = 1.f - wx1;
            int iy0 = (int)y0f, ix0 = (int)x0f;
            int iy1 = iy0 + 1,  ix1 = ix0 + 1;
            bool vy0 = (iy0 >= 0) && (iy0 < H_);
            bool vy1 = (iy1 >= 0) && (iy1 < H_);
            bool vx0 = (ix0 >= 0) && (ix0 < W_);
            bool vx1 = (ix1 >= 0) && (ix1 < W_);
            int cy0 = min(max(iy0, 0), H_ - 1), cy1 = min(max(iy1, 0), H_ - 1);
            int cx0 = min(max(ix0, 0), W_ - 1), cx1 = min(max(ix1, 0), W_ - 1);
            float w00 = (vy0 && vx0) ? wy0 * wx0 * m : 0.f;
            float w01 = (vy0 && vx1) ? wy0 * wx1 * m : 0.f;
            float w10 = (vy1 && vx0) ? wy1 * wx0 * m : 0.f;
            float w11 = (vy1 && vx1) ? wy1 * wx1 * m : 0.f;
            size_t r0 = (size_t)cy0 * W_, r1 = (size_t)cy1 * W_;

            #pragma unroll
            for (int c = 0; c < 8; ++c) {
                const float* xp = x + (size_t)(b * 64 + g * 8 + c) * HW_;
                float v = w00 * xp[r0 + cx0] + w01 * xp[r0 + cx1]
                        + w10 * xp[r1 + cx0] + w11 * xp[r1 + cx1];
                #pragma unroll
                for (int o4i = 0; o4i < 16; ++o4i) {
                    float4 wv = *reinterpret_cast<const float4*>(&s_w[c][t][o4i * 4]);
                    acc[o4i * 4 + 0] += v * wv.x;
                    acc[o4i * 4 + 1] += v * wv.y;
                    acc[o4i * 4 + 2] += v * wv.z;
                    acc[o4i * 4 + 3] += v * wv.w;
                }
            }
        }
    }
    #pragma unroll
    for (int o = 0; o < 64; ++o)
        out[(size_t)(b * 64 + o) * HW_ + pix] = acc[o];
}

// ---------------------------------------------------------------------------
extern "C" void kernel_launch(void* const* d_in, const int* in_sizes, int n_in,
                              void* d_out, int out_size, void* d_ws, size_t ws_size,
                              hipStream_t stream)
{
    const float* cfw  = (const float*)d_in[0];   // B,64,H,W
    const float* fpro = (const float*)d_in[1];   // B,64,H,W
    const float* fprv = (const float*)d_in[2];   // B,64,H,W
    const float* fl1  = (const float*)d_in[3];   // B,2,H,W
    const float* fl2  = (const float*)d_in[4];   // B,2,H,W
    const float* w1   = (const float*)d_in[5];   // 64,196,3,3
    const float* b1   = (const float*)d_in[6];
    const float* w2   = (const float*)d_in[7];   // 64,64,3,3
    const float* b2   = (const float*)d_in[8];
    const float* w3   = (const float*)d_in[9];   // 64,64,3,3
    const float* b3   = (const float*)d_in[10];
    const float* w4   = (const float*)d_in[11];  // 216,64,3,3
    const float* b4   = (const float*)d_in[12];
    const float* wdef = (const float*)d_in[13];  // 64,64,3,3
    const float* bdef = (const float*)d_in[14];
    float* out = (float*)d_out;

    const size_t N1 = (size_t)B_ * OC_ * HW_;        // 7,864,320 floats
    float* wsA = (float*)d_ws;                       // o1 / o3
    float* wsB = wsA + N1;                           // o2
    float* wsC = wsB;                                // o4 (216ch) — overlaps dead o2

    dim3 blk(32, 8);
    dim3 grid13(W_ / 32, H_ / 16, B_);               // PX=2 -> tile 32x16
    dim3 grid4 (W_ / 32, H_ / 16, B_ * 6);           // OCB=36, 6 oc-blocks

    // conv1: concat(196) -> 64, lrelu
    conv3x3_k<CIN1, 64, 2, true, true><<<grid13, blk, 0, stream>>>(
        cfw, fpro, fprv, fl1, fl2, w1, b1, wsA, 1, 64);
    // conv2: 64 -> 64, lrelu
    conv3x3_k<64, 64, 2, true, false><<<grid13, blk, 0, stream>>>(
        wsA, nullptr, nullptr, nullptr, nullptr, w2, b2, wsB, 1, 64);
    // conv3: 64 -> 64, lrelu (write back to A)
    conv3x3_k<64, 64, 2, true, false><<<grid13, blk, 0, stream>>>(
        wsB, nullptr, nullptr, nullptr, nullptr, w3, b3, wsA, 1, 64);
    // conv4: 64 -> 216, no act (write to C = former B region; fits in ws)
    conv3x3_k<64, 36, 2, false, false><<<grid4, blk, 0, stream>>>(
        wsA, nullptr, nullptr, nullptr, nullptr, w4, b4, wsC, 6, 216);
    // fused offset decode + deformable conv
    deform_k<<<dim3((B_ * HW_) / 256), dim3(256), 0, stream>>>(
        cfw, wsC, fl1, fl2, wdef, bdef, out);
}

// Round 2
// 998.453 us; speedup vs baseline: 1.8805x; 1.8805x over previous
//
#include <hip/hip_runtime.h>
#include <hip/hip_bf16.h>
#include <math.h>

typedef __attribute__((ext_vector_type(8))) short short8;
typedef __attribute__((ext_vector_type(4))) float f32x4;

constexpr int B_ = 8, H_ = 96, W_ = 160;
constexpr int HW_ = H_ * W_;
constexpr int NPIX = B_ * HW_;        // 122880
constexpr int G_ = 8;

__device__ __forceinline__ unsigned short f2bf(float f) {
    unsigned int u = __builtin_bit_cast(unsigned int, f);
    u += 0x7FFFu + ((u >> 16) & 1u);          // RNE
    return (unsigned short)(u >> 16);
}
__device__ __forceinline__ float bf2f(unsigned short s) {
    unsigned int u = ((unsigned int)s) << 16;
    return __builtin_bit_cast(float, u);
}

// ---------------------------------------------------------------------------
// Prep 1: concat inputs -> NHWC bf16, C padded to 224 (ch 196..223 = 0)
// ---------------------------------------------------------------------------
__global__ __launch_bounds__(256) void prep_x1(
    const float* __restrict__ cfw, const float* __restrict__ fpro,
    const float* __restrict__ fprv, const float* __restrict__ f1,
    const float* __restrict__ f2, unsigned short* __restrict__ X1)
{
    int idx = blockIdx.x * 256 + threadIdx.x;   // NPIX*224 total, exact grid
    int c = idx % 224;
    int pix = idx / 224;
    int b = pix / HW_;
    int hw = pix % HW_;
    float v = 0.f;
    if (c < 64)       v = cfw [((size_t)b * 64 + c      ) * HW_ + hw];
    else if (c < 128) v = fpro[((size_t)b * 64 + (c-64) ) * HW_ + hw];
    else if (c < 192) v = fprv[((size_t)b * 64 + (c-128)) * HW_ + hw];
    else if (c < 194) v = f1  [((size_t)b * 2  + (c-192)) * HW_ + hw];
    else if (c < 196) v = f2  [((size_t)b * 2  + (c-194)) * HW_ + hw];
    X1[idx] = f2bf(v);
}

// ---------------------------------------------------------------------------
// Prep 2: pack conv weights (OIHW fp32) into MFMA B-fragment order bf16.
// Layout: Bt[t][ck][nf][lane][8] ; B-frag: n = nf*16 + (lane&15),
// k = ck*32 + (lane>>4)*8 + j  (k indexes input channel).
// ---------------------------------------------------------------------------
__global__ __launch_bounds__(256) void prep_w(
    const float* __restrict__ w, unsigned short* __restrict__ Bt,
    int Cin, int KCH, int Nout, int NFTOT)
{
    int idx = blockIdx.x * 256 + threadIdx.x;
    int total = 9 * KCH * NFTOT * 64;
    if (idx >= total) return;
    int lane = idx & 63;
    int r = idx >> 6;
    int nf = r % NFTOT; r /= NFTOT;
    int ck = r % KCH;
    int t  = r / KCH;
    int n  = nf * 16 + (lane & 15);
    int kb = ck * 32 + (lane >> 4) * 8;
    short8 o;
    #pragma unroll
    for (int j = 0; j < 8; ++j) {
        int c = kb + j;
        float v = (c < Cin && n < Nout) ? w[((size_t)n * Cin + c) * 9 + t] : 0.f;
        o[j] = (short)f2bf(v);
    }
    *(short8*)(Bt + (size_t)idx * 8) = o;
}

// ---------------------------------------------------------------------------
// MFMA implicit-GEMM 3x3 conv, pad=1. X: NHWC bf16 (C = KCH*32).
// Block 256 = 4 waves; wave = 32 pixels x NF*16 oc (2 m-frags x NF n-frags).
// No LDS. A-frags from global NHWC (L1-cached tile), B-frags prepacked.
// ---------------------------------------------------------------------------
template<int KCH, int NFTOT, int NF, bool RELU>
__global__ __launch_bounds__(256) void conv_mfma(
    const unsigned short* __restrict__ X, const unsigned short* __restrict__ Bt,
    const float* __restrict__ bias, unsigned short* __restrict__ Y,
    int CoutTot, int fBase0)
{
    constexpr int CPAD = KCH * 32;
    const int lane = threadIdx.x & 63;
    const int wv   = threadIdx.x >> 6;
    const int m0   = blockIdx.x * 128 + wv * 32;
    const int fBase = fBase0 + blockIdx.y * NF;
    const int lm = lane & 15;
    const int kj = (lane >> 4) * 8;

    int p[2], hh[2], wp[2];
    #pragma unroll
    for (int mf = 0; mf < 2; ++mf) {
        int pm = m0 + mf * 16 + lm;
        p[mf] = pm;
        hh[mf] = (pm / W_) % H_;
        wp[mf] = pm % W_;
    }

    f32x4 acc[2][NF];
    #pragma unroll
    for (int nf = 0; nf < NF; ++nf) {
        int oc = (fBase + nf) * 16 + lm;
        float bv = (oc < CoutTot) ? bias[oc] : 0.f;
        f32x4 a = {bv, bv, bv, bv};
        acc[0][nf] = a; acc[1][nf] = a;
    }

    const short8 zero = {0,0,0,0,0,0,0,0};

    #pragma unroll
    for (int ck = 0; ck < KCH; ++ck) {
        const int c0 = ck * 32;
        #pragma unroll
        for (int t = 0; t < 9; ++t) {
            const int di = t / 3 - 1, dj = t % 3 - 1;
            const unsigned short* bp =
                Bt + (((size_t)(t * KCH + ck) * NFTOT + fBase) * 64 + lane) * 8;
            short8 bfr[NF];
            #pragma unroll
            for (int nf = 0; nf < NF; ++nf)
                bfr[nf] = *(const short8*)(bp + (size_t)nf * 512);
            #pragma unroll
            for (int mf = 0; mf < 2; ++mf) {
                bool val = ((unsigned)(hh[mf] + di) < (unsigned)H_) &&
                           ((unsigned)(wp[mf] + dj) < (unsigned)W_);
                const unsigned short* ap =
                    X + (size_t)(p[mf] + di * W_ + dj) * CPAD + c0 + kj;
                short8 afr = val ? *(const short8*)ap : zero;
                #pragma unroll
                for (int nf = 0; nf < NF; ++nf)
                    acc[mf][nf] = __builtin_amdgcn_mfma_f32_16x16x32_bf16(
                        afr, bfr[nf], acc[mf][nf], 0, 0, 0);
            }
        }
    }

    // D frag: col(oc) = lane&15, row(pixel) = (lane>>4)*4 + reg
    const int prow = (lane >> 4) * 4;
    #pragma unroll
    for (int mf = 0; mf < 2; ++mf)
        #pragma unroll
        for (int nf = 0; nf < NF; ++nf) {
            int oc = (fBase + nf) * 16 + lm;
            if (oc < CoutTot) {
                #pragma unroll
                for (int r = 0; r < 4; ++r) {
                    int pix = m0 + mf * 16 + prow + r;
                    float v = acc[mf][nf][r];
                    if (RELU) v = (v >= 0.f) ? v : 0.1f * v;
                    Y[(size_t)pix * CoutTot + oc] = f2bf(v);
                }
            }
        }
}

// ---------------------------------------------------------------------------
// Deformable conv: fp32 VALU. o4 is NHWC bf16 (216 ch/pixel).
// Block 128 thr = 2 waves; thread = 2 pixels x 32 oc.
// ---------------------------------------------------------------------------
__global__ __launch_bounds__(128) void deform_k(
    const float* __restrict__ x,            // B,64,H,W fp32 NCHW
    const unsigned short* __restrict__ o4,  // NPIX x 216 bf16 NHWC
    const float* __restrict__ f1, const float* __restrict__ f2,
    const float* __restrict__ wgt,          // 64,64,3,3 fp32
    const float* __restrict__ bia,
    float* __restrict__ out)                // B,64,H,W fp32 NCHW
{
    __shared__ __align__(16) float s_w[8][9][64];   // cin-in-group, tap, oc

    const int tid = threadIdx.x;
    const int pairIdx = blockIdx.x * 64 + (tid >> 1);
    const int och = (tid & 1) * 32;
    const int p0 = pairIdx * 2;                 // p0 even; p0,p0+1 same row
    const int b  = p0 / HW_;
    const int hw0 = p0 % HW_;
    const int h  = hw0 / W_;
    const int w0 = hw0 % W_;

    float acc[2][32];
    #pragma unroll
    for (int o = 0; o < 32; ++o) {
        float bv = bia[och + o];
        acc[0][o] = bv; acc[1][o] = bv;
    }

    const size_t bF = (size_t)b * 2 * HW_;

    for (int g = 0; g < G_; ++g) {
        __syncthreads();
        for (int idx = tid; idx < 8 * 9 * 64; idx += 128) {
            int oc = idx & 63;          // oc fastest -> conflict-free writes
            int r  = idx >> 6;
            int c  = r / 9;
            int t  = r % 9;
            s_w[c][t][oc] = wgt[((size_t)oc * 64 + g * 8 + c) * 9 + t];
        }
        __syncthreads();

        const float* fl = (g < 4) ? f1 : f2;
        float fy[2], fx[2];
        #pragma unroll
        for (int q = 0; q < 2; ++q) {
            fy[q] = fl[bF + (size_t)HW_ + hw0 + q];
            fx[q] = fl[bF + hw0 + q];
        }

        #pragma unroll
        for (int t = 0; t < 9; ++t) {
            const int i = t / 3, j = t % 3;
            float w00[2], w01[2], w10[2], w11[2];
            size_t r0[2], r1[2];
            int cx0[2], cx1[2];
            #pragma unroll
            for (int q = 0; q < 2; ++q) {
                size_t base = (size_t)(p0 + q) * 216;
                float dy = bf2f(o4[base + (size_t)(g * 9 + t) * 2]) + fy[q];
                float dx = bf2f(o4[base + (size_t)(g * 9 + t) * 2 + 1]) + fx[q];
                float mr = bf2f(o4[base + 144 + g * 9 + t]);
                float m  = 1.f / (1.f + expf(-mr));

                float ys = dy + (float)(h - 1 + i);
                float xs = dx + (float)(w0 + q - 1 + j);
                float y0f = floorf(ys), x0f = floorf(xs);
                float wy1 = ys - y0f, wx1 = xs - x0f;
                float wy0 = 1.f - wy1, wx0 = 1.f - wx1;
                int iy0 = (int)y0f, ix0 = (int)x0f;
                int iy1 = iy0 + 1,  ix1 = ix0 + 1;
                bool vy0 = (iy0 >= 0) && (iy0 < H_);
                bool vy1 = (iy1 >= 0) && (iy1 < H_);
                bool vx0 = (ix0 >= 0) && (ix0 < W_);
                bool vx1 = (ix1 >= 0) && (ix1 < W_);
                int cy0 = min(max(iy0, 0), H_ - 1), cy1 = min(max(iy1, 0), H_ - 1);
                cx0[q] = min(max(ix0, 0), W_ - 1);
                cx1[q] = min(max(ix1, 0), W_ - 1);
                w00[q] = (vy0 && vx0) ? wy0 * wx0 * m : 0.f;
                w01[q] = (vy0 && vx1) ? wy0 * wx1 * m : 0.f;
                w10[q] = (vy1 && vx0) ? wy1 * wx0 * m : 0.f;
                w11[q] = (vy1 && vx1) ? wy1 * wx1 * m : 0.f;
                r0[q] = (size_t)cy0 * W_;
                r1[q] = (size_t)cy1 * W_;
            }
            #pragma unroll
            for (int c = 0; c < 8; ++c) {
                const float* xp = x + (size_t)(b * 64 + g * 8 + c) * HW_;
                float v[2];
                #pragma unroll
                for (int q = 0; q < 2; ++q)
                    v[q] = w00[q] * xp[r0[q] + cx0[q]] + w01[q] * xp[r0[q] + cx1[q]]
                         + w10[q] * xp[r1[q] + cx0[q]] + w11[q] * xp[r1[q] + cx1[q]];
                #pragma unroll
                for (int o4i = 0; o4i < 8; ++o4i) {
                    float4 wv = *reinterpret_cast<const float4*>(&s_w[c][t][och + o4i * 4]);
                    #pragma unroll
                    for (int q = 0; q < 2; ++q) {
                        acc[q][o4i * 4 + 0] += v[q] * wv.x;
                        acc[q][o4i * 4 + 1] += v[q] * wv.y;
                        acc[q][o4i * 4 + 2] += v[q] * wv.z;
                        acc[q][o4i * 4 + 3] += v[q] * wv.w;
                    }
                }
            }
        }
    }
    #pragma unroll
    for (int q = 0; q < 2; ++q)
        #pragma unroll
        for (int o = 0; o < 32; ++o)
            out[((size_t)(b * 64 + och + o)) * HW_ + hw0 + q] = acc[q][o];
}

// ---------------------------------------------------------------------------
extern "C" void kernel_launch(void* const* d_in, const int* in_sizes, int n_in,
                              void* d_out, int out_size, void* d_ws, size_t ws_size,
                              hipStream_t stream)
{
    const float* cfw  = (const float*)d_in[0];
    const float* fpro = (const float*)d_in[1];
    const float* fprv = (const float*)d_in[2];
    const float* fl1  = (const float*)d_in[3];
    const float* fl2  = (const float*)d_in[4];
    const float* w1   = (const float*)d_in[5];
    const float* b1   = (const float*)d_in[6];
    const float* w2   = (const float*)d_in[7];
    const float* b2   = (const float*)d_in[8];
    const float* w3   = (const float*)d_in[9];
    const float* b3   = (const float*)d_in[10];
    const float* w4   = (const float*)d_in[11];
    const float* b4   = (const float*)d_in[12];
    const float* wdef = (const float*)d_in[13];
    const float* bdef = (const float*)d_in[14];
    float* out = (float*)d_out;

    // ---- workspace layout (bytes) ----
    // [0, 55,050,240)                X1 (NHWC bf16, C=224); later o3 (C=64)
    // [55,050,240, 108,134,400)     o4 (NHWC bf16, C=216); earlier o1,o2
    // [108,134,400, ...)            packed weights Bt1..Bt4
    char* ws = (char*)d_ws;
    unsigned short* X1  = (unsigned short*)(ws);
    unsigned short* o3  = (unsigned short*)(ws);                 // alias X1
    unsigned short* o1  = (unsigned short*)(ws + 55050240);
    unsigned short* o2  = (unsigned short*)(ws + 55050240 + 15728640);
    unsigned short* o4b = (unsigned short*)(ws + 55050240);      // alias o1,o2
    unsigned short* Bt1 = (unsigned short*)(ws + 108134400);
    unsigned short* Bt2 = (unsigned short*)(ws + 108134400 + 258048);
    unsigned short* Bt3 = (unsigned short*)(ws + 108134400 + 258048 + 73728);
    unsigned short* Bt4 = (unsigned short*)(ws + 108134400 + 258048 + 73728 + 73728);

    // prep: concat -> NHWC bf16 (C=224)
    prep_x1<<<dim3((NPIX * 224) / 256), dim3(256), 0, stream>>>(
        cfw, fpro, fprv, fl1, fl2, X1);
    // prep: pack weights
    prep_w<<<dim3((9*7*4*64 + 255) / 256), dim3(256), 0, stream>>>(w1, Bt1, 196, 7, 64, 4);
    prep_w<<<dim3((9*2*4*64 + 255) / 256), dim3(256), 0, stream>>>(w2, Bt2, 64, 2, 64, 4);
    prep_w<<<dim3((9*2*4*64 + 255) / 256), dim3(256), 0, stream>>>(w3, Bt3, 64, 2, 64, 4);
    prep_w<<<dim3((9*2*14*64 + 255) / 256), dim3(256), 0, stream>>>(w4, Bt4, 64, 2, 216, 14);

    dim3 blk(256);
    dim3 gridM(NPIX / 128, 1);
    // conv1: 224(padded 196) -> 64, lrelu
    conv_mfma<7, 4, 4, true><<<gridM, blk, 0, stream>>>(X1, Bt1, b1, o1, 64, 0);
    // conv2, conv3
    conv_mfma<2, 4, 4, true><<<gridM, blk, 0, stream>>>(o1, Bt2, b2, o2, 64, 0);
    conv_mfma<2, 4, 4, true><<<gridM, blk, 0, stream>>>(o2, Bt3, b3, o3, 64, 0);
    // conv4: 64 -> 216 (pad 224), no act. frags 0..11 then 12..13
    conv_mfma<2, 14, 4, false><<<dim3(NPIX / 128, 3), blk, 0, stream>>>(o3, Bt4, b4, o4b, 216, 0);
    conv_mfma<2, 14, 2, false><<<dim3(NPIX / 128, 1), blk, 0, stream>>>(o3, Bt4, b4, o4b, 216, 12);
    // deformable conv
    deform_k<<<dim3(NPIX / 128), dim3(128), 0, stream>>>(
        cfw, o4b, fl1, fl2, wdef, bdef, out);
}

// Round 3
// 691.800 us; speedup vs baseline: 2.7140x; 1.4433x over previous
//
#include <hip/hip_runtime.h>
#include <hip/hip_bf16.h>
#include <math.h>

typedef __attribute__((ext_vector_type(8))) short short8;
typedef __attribute__((ext_vector_type(4))) float f32x4;

constexpr int B_ = 8, H_ = 96, W_ = 160;
constexpr int HW_ = H_ * W_;
constexpr int NPIX = B_ * HW_;        // 122880

__device__ __forceinline__ unsigned short f2bf(float f) {
    unsigned int u = __builtin_bit_cast(unsigned int, f);
    u += 0x7FFFu + ((u >> 16) & 1u);          // RNE
    return (unsigned short)(u >> 16);
}
__device__ __forceinline__ float bf2f(unsigned short s) {
    unsigned int u = ((unsigned int)s) << 16;
    return __builtin_bit_cast(float, u);
}
__device__ __forceinline__ unsigned int cvt_pk_bf16(float lo, float hi) {
    unsigned int r;
    asm volatile("v_cvt_pk_bf16_f32 %0, %1, %2" : "=v"(r) : "v"(lo), "v"(hi));
    return r;   // D[15:0]=bf16(lo), D[31:16]=bf16(hi)
}

// ---------------------------------------------------------------------------
// Prep 1: concat inputs -> NHWC bf16 [NPIX][224] (ch 196..223 = 0), pair-packed
// ---------------------------------------------------------------------------
__global__ __launch_bounds__(256) void prep_x1(
    const float* __restrict__ cfw, const float* __restrict__ fpro,
    const float* __restrict__ fprv, const float* __restrict__ f1,
    const float* __restrict__ f2, unsigned int* __restrict__ X1p)
{
    int idx = blockIdx.x * 256 + threadIdx.x;   // NPIX*112, exact grid
    int cp = idx % 112;
    int pix = idx / 112;
    int b = pix / HW_;
    int hw = pix % HW_;
    int c = cp * 2;
    float v0 = 0.f, v1 = 0.f;
    const float* src = nullptr; int sc = 0, nc = 0;
    if (c < 64)       { src = cfw;  sc = c;       nc = 64; }
    else if (c < 128) { src = fpro; sc = c - 64;  nc = 64; }
    else if (c < 192) { src = fprv; sc = c - 128; nc = 64; }
    else if (c < 194) { src = f1;   sc = c - 192; nc = 2;  }
    else if (c < 196) { src = f2;   sc = c - 194; nc = 2;  }
    if (src) {
        v0 = src[((size_t)b * nc + sc    ) * HW_ + hw];
        v1 = src[((size_t)b * nc + sc + 1) * HW_ + hw];
    }
    X1p[idx] = (unsigned int)f2bf(v0) | ((unsigned int)f2bf(v1) << 16);
}

// ---------------------------------------------------------------------------
// Prep 2: pack conv weights (OIHW fp32) -> MFMA B-frag order bf16.
// Bt[t][ck][nf][lane][8]; n = nf*16+(lane&15), k = ck*32+(lane>>4)*8+j (input ch)
// ---------------------------------------------------------------------------
__global__ __launch_bounds__(256) void prep_w(
    const float* __restrict__ w, unsigned short* __restrict__ Bt,
    int Cin, int KCH, int Nout, int NFTOT)
{
    int idx = blockIdx.x * 256 + threadIdx.x;
    int total = 9 * KCH * NFTOT * 64;
    if (idx >= total) return;
    int lane = idx & 63;
    int r = idx >> 6;
    int nf = r % NFTOT; r /= NFTOT;
    int ck = r % KCH;
    int t  = r / KCH;
    int n  = nf * 16 + (lane & 15);
    int kb = ck * 32 + (lane >> 4) * 8;
    short8 o;
    #pragma unroll
    for (int j = 0; j < 8; ++j) {
        int c = kb + j;
        float v = (c < Cin && n < Nout) ? w[((size_t)n * Cin + c) * 9 + t] : 0.f;
        o[j] = (short)f2bf(v);
    }
    *(short8*)(Bt + (size_t)idx * 8) = o;
}

// ---------------------------------------------------------------------------
// Prep 3: pack deform weights. Btd[g][ck(3)][nf(4)][lane][8];
// k (within group, 0..95) = t*8 + c ; weight = wdef[oc][g*8+c][t], t>=9 -> 0
// ---------------------------------------------------------------------------
__global__ __launch_bounds__(256) void prep_wd(
    const float* __restrict__ w, unsigned short* __restrict__ Btd)
{
    int idx = blockIdx.x * 256 + threadIdx.x;   // 8*3*4*64 = 6144
    if (idx >= 8 * 3 * 4 * 64) return;
    int lane = idx & 63;
    int r = idx >> 6;
    int nf = r % 4; r >>= 2;
    int ck = r % 3;
    int g  = r / 3;
    int n  = nf * 16 + (lane & 15);             // oc
    int kb = ck * 32 + (lane >> 4) * 8;
    short8 o;
    #pragma unroll
    for (int j = 0; j < 8; ++j) {
        int k = kb + j;
        int t = k >> 3, c = k & 7;
        float v = (t < 9) ? w[((size_t)n * 64 + g * 8 + c) * 9 + t] : 0.f;
        o[j] = (short)f2bf(v);
    }
    *(short8*)(Btd + (size_t)idx * 8) = o;
}

// ---------------------------------------------------------------------------
// MFMA implicit-GEMM 3x3 conv, pad=1. X: NHWC bf16 (C = KCH*32).
// MODE 0: store bf16 NHWC (optional lrelu).
// MODE 1 (conv4): fold flow-add (oc<144) / sigmoid (oc>=144), store grouped
//                 o4g[g][NPIX][28] bf16: [t*2+d] = offset, [18+t] = mask.
// ---------------------------------------------------------------------------
template<int KCH, int NFTOT, int NF, bool RELU, int MODE>
__global__ __launch_bounds__(256) void conv_mfma(
    const unsigned short* __restrict__ X, const unsigned short* __restrict__ Bt,
    const float* __restrict__ bias, unsigned short* __restrict__ Y,
    int CoutTot, int fBase0,
    const float* __restrict__ f1, const float* __restrict__ f2)
{
    constexpr int CPAD = KCH * 32;
    const int lane = threadIdx.x & 63;
    const int wv   = threadIdx.x >> 6;
    const int m0   = blockIdx.x * 128 + wv * 32;
    const int fBase = fBase0 + blockIdx.y * NF;
    const int lm = lane & 15;
    const int kj = (lane >> 4) * 8;

    int p[2], hh[2], wp[2];
    #pragma unroll
    for (int mf = 0; mf < 2; ++mf) {
        int pm = m0 + mf * 16 + lm;
        p[mf] = pm;
        hh[mf] = (pm / W_) % H_;
        wp[mf] = pm % W_;
    }

    f32x4 acc[2][NF];
    #pragma unroll
    for (int nf = 0; nf < NF; ++nf) {
        int oc = (fBase + nf) * 16 + lm;
        float bv = (oc < CoutTot) ? bias[oc] : 0.f;
        f32x4 a = {bv, bv, bv, bv};
        acc[0][nf] = a; acc[1][nf] = a;
    }

    const short8 zero = {0,0,0,0,0,0,0,0};

    #pragma unroll
    for (int ck = 0; ck < KCH; ++ck) {
        const int c0 = ck * 32;
        #pragma unroll
        for (int t = 0; t < 9; ++t) {
            const int di = t / 3 - 1, dj = t % 3 - 1;
            const unsigned short* bp =
                Bt + (((size_t)(t * KCH + ck) * NFTOT + fBase) * 64 + lane) * 8;
            short8 bfr[NF];
            #pragma unroll
            for (int nf = 0; nf < NF; ++nf)
                bfr[nf] = *(const short8*)(bp + (size_t)nf * 512);
            #pragma unroll
            for (int mf = 0; mf < 2; ++mf) {
                bool val = ((unsigned)(hh[mf] + di) < (unsigned)H_) &&
                           ((unsigned)(wp[mf] + dj) < (unsigned)W_);
                const unsigned short* ap =
                    X + (size_t)(p[mf] + di * W_ + dj) * CPAD + c0 + kj;
                short8 afr = val ? *(const short8*)ap : zero;
                #pragma unroll
                for (int nf = 0; nf < NF; ++nf)
                    acc[mf][nf] = __builtin_amdgcn_mfma_f32_16x16x32_bf16(
                        afr, bfr[nf], acc[mf][nf], 0, 0, 0);
            }
        }
    }

    const int prow = (lane >> 4) * 4;
    #pragma unroll
    for (int mf = 0; mf < 2; ++mf)
        #pragma unroll
        for (int nf = 0; nf < NF; ++nf) {
            int oc = (fBase + nf) * 16 + lm;
            if (oc < CoutTot) {
                #pragma unroll
                for (int r = 0; r < 4; ++r) {
                    int pix = m0 + mf * 16 + prow + r;
                    float v = acc[mf][nf][r];
                    if (MODE == 0) {
                        if (RELU) v = (v >= 0.f) ? v : 0.1f * v;
                        Y[(size_t)pix * CoutTot + oc] = f2bf(v);
                    } else {
                        int bb = pix / HW_, hw = pix % HW_;
                        if (oc < 144) {
                            int pr = oc >> 1, d = oc & 1;
                            int g = pr / 9, t = pr - g * 9;
                            const float* fl = (g < 4) ? f1 : f2;
                            v += fl[((size_t)bb * 2 + (d ^ 1)) * HW_ + hw];
                            Y[((size_t)g * NPIX + pix) * 28 + t * 2 + d] = f2bf(v);
                        } else {
                            int mi = oc - 144;
                            int g = mi / 9, t = mi - g * 9;
                            v = 1.f / (1.f + expf(-v));
                            Y[((size_t)g * NPIX + pix) * 28 + 18 + t] = f2bf(v);
                        }
                    }
                }
            }
        }
}

// ---------------------------------------------------------------------------
// Fused deformable conv: sample -> LDS (XOR-swizzled) -> MFMA.
// Block = 128 pixels, 256 threads (4 waves, wave = 32 pix x 64 oc).
// LDS samp: [128 pix][16 slots][8 bf16] (256 B/row), slot = t ^ (pix&7).
// K per group = 96 (taps 0..8 -> cols t*8..t*8+8, cols 72..95 stay zero).
// ---------------------------------------------------------------------------
__global__ __launch_bounds__(256) void deform_mfma(
    const unsigned short* __restrict__ X1,   // [NPIX][224] bf16 (cols 0..63 = x)
    const unsigned short* __restrict__ o4g,  // [8][NPIX][28] bf16
    const unsigned short* __restrict__ Btd,  // [8][3][4][64][8] bf16
    const float* __restrict__ bia,           // 64
    float* __restrict__ out)                 // B,64,H,W fp32 NCHW
{
    __shared__ __align__(16) char lds[128 * 65 * 4];   // 33280 B
    float* sout = (float*)lds;                         // [128][65]

    const int tid  = threadIdx.x;
    const int lane = tid & 63;
    const int wv   = tid >> 6;
    const int lm   = lane & 15;
    const int pix0 = blockIdx.x * 128;
    const int b    = pix0 / HW_;
    const int hw0  = pix0 % HW_;

    // zero samp region once (slots never written stay zero across all groups)
    {
        uint4 z = {0u, 0u, 0u, 0u};
        #pragma unroll
        for (int i = 0; i < 8; ++i)
            ((uint4*)lds)[i * 256 + tid] = z;
    }

    f32x4 acc[2][4];
    #pragma unroll
    for (int nf = 0; nf < 4; ++nf) {
        float bv = bia[nf * 16 + lm];
        f32x4 a = {bv, bv, bv, bv};
        acc[0][nf] = a; acc[1][nf] = a;
    }

    for (int g = 0; g < 8; ++g) {
        __syncthreads();   // prev group's MFMA reads done (also covers zero-init)
        // ---- sampling: 1152 units (pix 0..127 x t 0..8), t uniform per wave ----
        #pragma unroll
        for (int it = 0; it < 5; ++it) {
            int u = it * 256 + tid;
            if (u < 1152) {
                int t   = u >> 7;
                int pix = u & 127;
                int hw = hw0 + pix;
                int h = hw / W_;
                int w = hw - h * W_;
                size_t ob = ((size_t)g * NPIX + pix0 + pix) * 28;
                unsigned int dd = *(const unsigned int*)(o4g + ob + t * 2);
                float dy = bf2f((unsigned short)(dd & 0xFFFFu));
                float dx = bf2f((unsigned short)(dd >> 16));
                float m  = bf2f(o4g[ob + 18 + t]);

                float ys = dy + (float)(h - 1 + t / 3);
                float xs = dx + (float)(w - 1 + t % 3);
                float y0f = floorf(ys), x0f = floorf(xs);
                float wy1 = ys - y0f, wx1 = xs - x0f;
                float wy0 = 1.f - wy1, wx0 = 1.f - wx1;
                int iy0 = (int)y0f, ix0 = (int)x0f;
                int iy1 = iy0 + 1,  ix1 = ix0 + 1;
                bool vy0 = (unsigned)iy0 < (unsigned)H_;
                bool vy1 = (unsigned)iy1 < (unsigned)H_;
                bool vx0 = (unsigned)ix0 < (unsigned)W_;
                bool vx1 = (unsigned)ix1 < (unsigned)W_;
                int cy0 = min(max(iy0, 0), H_ - 1), cy1 = min(max(iy1, 0), H_ - 1);
                int cx0 = min(max(ix0, 0), W_ - 1), cx1 = min(max(ix1, 0), W_ - 1);
                float w00 = (vy0 && vx0) ? wy0 * wx0 * m : 0.f;
                float w01 = (vy0 && vx1) ? wy0 * wx1 * m : 0.f;
                float w10 = (vy1 && vx0) ? wy1 * wx0 * m : 0.f;
                float w11 = (vy1 && vx1) ? wy1 * wx1 * m : 0.f;

                size_t r0 = (size_t)b * HW_ + (size_t)cy0 * W_;
                size_t r1 = (size_t)b * HW_ + (size_t)cy1 * W_;
                const int gc = g * 8;
                uint4 c00 = *(const uint4*)(X1 + (r0 + cx0) * 224 + gc);
                uint4 c01 = *(const uint4*)(X1 + (r0 + cx1) * 224 + gc);
                uint4 c10 = *(const uint4*)(X1 + (r1 + cx0) * 224 + gc);
                uint4 c11 = *(const uint4*)(X1 + (r1 + cx1) * 224 + gc);

                float a8[8];
                #pragma unroll
                for (int i = 0; i < 8; ++i) a8[i] = 0.f;
                const unsigned int u00[4] = {c00.x, c00.y, c00.z, c00.w};
                const unsigned int u01[4] = {c01.x, c01.y, c01.z, c01.w};
                const unsigned int u10[4] = {c10.x, c10.y, c10.z, c10.w};
                const unsigned int u11[4] = {c11.x, c11.y, c11.z, c11.w};
                #pragma unroll
                for (int i = 0; i < 4; ++i) {
                    a8[2*i]   += w00 * __builtin_bit_cast(float, u00[i] << 16);
                    a8[2*i+1] += w00 * __builtin_bit_cast(float, u00[i] & 0xFFFF0000u);
                    a8[2*i]   += w01 * __builtin_bit_cast(float, u01[i] << 16);
                    a8[2*i+1] += w01 * __builtin_bit_cast(float, u01[i] & 0xFFFF0000u);
                    a8[2*i]   += w10 * __builtin_bit_cast(float, u10[i] << 16);
                    a8[2*i+1] += w10 * __builtin_bit_cast(float, u10[i] & 0xFFFF0000u);
                    a8[2*i]   += w11 * __builtin_bit_cast(float, u11[i] << 16);
                    a8[2*i+1] += w11 * __builtin_bit_cast(float, u11[i] & 0xFFFF0000u);
                }
                uint4 ov;
                ov.x = cvt_pk_bf16(a8[0], a8[1]);
                ov.y = cvt_pk_bf16(a8[2], a8[3]);
                ov.z = cvt_pk_bf16(a8[4], a8[5]);
                ov.w = cvt_pk_bf16(a8[6], a8[7]);
                int slot = t ^ (pix & 7);
                *(uint4*)(lds + pix * 256 + slot * 16) = ov;
            }
        }
        __syncthreads();
        // ---- MFMA: K=96 over this group ----
        #pragma unroll
        for (int ck = 0; ck < 3; ++ck) {
            const short8* bpp = (const short8*)Btd + ((size_t)(g * 3 + ck) * 4) * 64 + lane;
            short8 bfr[4];
            #pragma unroll
            for (int nf = 0; nf < 4; ++nf) bfr[nf] = bpp[nf * 64];
            const int slotbase = ck * 4 + (lane >> 4);
            #pragma unroll
            for (int mf = 0; mf < 2; ++mf) {
                int row = wv * 32 + mf * 16 + lm;
                int slot = slotbase ^ (lm & 7);
                short8 afr = *(const short8*)(lds + row * 256 + slot * 16);
                #pragma unroll
                for (int nf = 0; nf < 4; ++nf)
                    acc[mf][nf] = __builtin_amdgcn_mfma_f32_16x16x32_bf16(
                        afr, bfr[nf], acc[mf][nf], 0, 0, 0);
            }
        }
    }

    // ---- epilogue: restage through LDS for coalesced NCHW stores ----
    __syncthreads();
    const int prow = (lane >> 4) * 4;
    #pragma unroll
    for (int mf = 0; mf < 2; ++mf)
        #pragma unroll
        for (int nf = 0; nf < 4; ++nf)
            #pragma unroll
            for (int r = 0; r < 4; ++r)
                sout[(wv * 32 + mf * 16 + prow + r) * 65 + nf * 16 + lm] = acc[mf][nf][r];
    __syncthreads();
    #pragma unroll
    for (int i = 0; i < 32; ++i) {
        int idx = i * 256 + tid;        // 8192 = 128 pix x 64 oc
        int oc = idx >> 7;
        int pp = idx & 127;
        out[((size_t)(b * 64 + oc)) * HW_ + hw0 + pp] = sout[pp * 65 + oc];
    }
}

// ---------------------------------------------------------------------------
extern "C" void kernel_launch(void* const* d_in, const int* in_sizes, int n_in,
                              void* d_out, int out_size, void* d_ws, size_t ws_size,
                              hipStream_t stream)
{
    const float* cfw  = (const float*)d_in[0];
    const float* fpro = (const float*)d_in[1];
    const float* fprv = (const float*)d_in[2];
    const float* fl1  = (const float*)d_in[3];
    const float* fl2  = (const float*)d_in[4];
    const float* w1   = (const float*)d_in[5];
    const float* b1   = (const float*)d_in[6];
    const float* w2   = (const float*)d_in[7];
    const float* b2   = (const float*)d_in[8];
    const float* w3   = (const float*)d_in[9];
    const float* b3   = (const float*)d_in[10];
    const float* w4   = (const float*)d_in[11];
    const float* b4   = (const float*)d_in[12];
    const float* wdef = (const float*)d_in[13];
    const float* bdef = (const float*)d_in[14];
    float* out = (float*)d_out;

    // ---- workspace layout (bytes) ----
    // [0, 55,050,240)               X1 [NPIX][224] bf16 (live until deform)
    // [55,050,240, 70,778,880)      buf1: o1, later o3
    // [70,778,880, 125,829,120)     o4g [8][NPIX][28] bf16; o2 at its start
    // [125,829,120, ~126.6 MB)      packed weights
    char* ws = (char*)d_ws;
    unsigned short* X1  = (unsigned short*)(ws);
    unsigned short* buf1= (unsigned short*)(ws + 55050240);   // o1 then o3
    unsigned short* o2  = (unsigned short*)(ws + 70778880);   // dead after conv3
    unsigned short* o4g = (unsigned short*)(ws + 70778880);   // clobbers o2 (OK)
    unsigned short* Bt1 = (unsigned short*)(ws + 125829120);
    unsigned short* Bt2 = (unsigned short*)(ws + 125829120 + 258048);
    unsigned short* Bt3 = (unsigned short*)(ws + 125829120 + 258048 + 73728);
    unsigned short* Bt4 = (unsigned short*)(ws + 125829120 + 258048 + 2*73728);
    unsigned short* Btd = (unsigned short*)(ws + 125829120 + 2*258048 + 2*73728);

    prep_x1<<<dim3((NPIX * 112) / 256), dim3(256), 0, stream>>>(
        cfw, fpro, fprv, fl1, fl2, (unsigned int*)X1);
    prep_w<<<dim3((9*7*4*64 + 255) / 256), dim3(256), 0, stream>>>(w1, Bt1, 196, 7, 64, 4);
    prep_w<<<dim3((9*2*4*64 + 255) / 256), dim3(256), 0, stream>>>(w2, Bt2, 64, 2, 64, 4);
    prep_w<<<dim3((9*2*4*64 + 255) / 256), dim3(256), 0, stream>>>(w3, Bt3, 64, 2, 64, 4);
    prep_w<<<dim3((9*2*14*64 + 255) / 256), dim3(256), 0, stream>>>(w4, Bt4, 64, 2, 216, 14);
    prep_wd<<<dim3((8*3*4*64 + 255) / 256), dim3(256), 0, stream>>>(wdef, Btd);

    dim3 blk(256);
    dim3 gridM(NPIX / 128, 1);
    // conv1: X1(196) -> o1 (buf1), lrelu
    conv_mfma<7, 4, 4, true, 0><<<gridM, blk, 0, stream>>>(X1, Bt1, b1, buf1, 64, 0, nullptr, nullptr);
    // conv2: o1 (buf1) -> o2, lrelu
    conv_mfma<2, 4, 4, true, 0><<<gridM, blk, 0, stream>>>(buf1, Bt2, b2, o2, 64, 0, nullptr, nullptr);
    // conv3: o2 -> o3 (buf1, o1 dead), lrelu
    conv_mfma<2, 4, 4, true, 0><<<gridM, blk, 0, stream>>>(o2, Bt3, b3, buf1, 64, 0, nullptr, nullptr);
    // conv4: o3 (buf1) -> o4g (clobbers o2, dead) with flow-add/sigmoid epilogue
    conv_mfma<2, 14, 4, false, 1><<<dim3(NPIX / 128, 3), blk, 0, stream>>>(buf1, Bt4, b4, o4g, 216, 0, fl1, fl2);
    conv_mfma<2, 14, 2, false, 1><<<dim3(NPIX / 128, 1), blk, 0, stream>>>(buf1, Bt4, b4, o4g, 216, 12, fl1, fl2);
    // fused deformable conv
    deform_mfma<<<dim3(NPIX / 128), blk, 0, stream>>>(X1, o4g, Btd, bdef, out);
}

// Round 4
// 495.735 us; speedup vs baseline: 3.7874x; 1.3955x over previous
//
#include <hip/hip_runtime.h>
#include <hip/hip_bf16.h>
#include <math.h>

typedef __attribute__((ext_vector_type(8))) short short8;
typedef __attribute__((ext_vector_type(4))) float f32x4;

constexpr int B_ = 8, H_ = 96, W_ = 160;
constexpr int HW_ = H_ * W_;
constexpr int NPIX = B_ * HW_;        // 122880

__device__ __forceinline__ unsigned short f2bf(float f) {
    unsigned int u = __builtin_bit_cast(unsigned int, f);
    u += 0x7FFFu + ((u >> 16) & 1u);          // RNE
    return (unsigned short)(u >> 16);
}
__device__ __forceinline__ float bf2f(unsigned short s) {
    unsigned int u = ((unsigned int)s) << 16;
    return __builtin_bit_cast(float, u);
}
__device__ __forceinline__ unsigned int cvt_pk_bf16(float lo, float hi) {
    unsigned int r;
    asm volatile("v_cvt_pk_bf16_f32 %0, %1, %2" : "=v"(r) : "v"(lo), "v"(hi));
    return r;   // D[15:0]=bf16(lo), D[31:16]=bf16(hi)
}

// ---------------------------------------------------------------------------
// Prep 1: concat inputs -> NHWC bf16 [NPIX][224] (ch 196..223 = 0), pair-packed
// ---------------------------------------------------------------------------
__global__ __launch_bounds__(256) void prep_x1(
    const float* __restrict__ cfw, const float* __restrict__ fpro,
    const float* __restrict__ fprv, const float* __restrict__ f1,
    const float* __restrict__ f2, unsigned int* __restrict__ X1p)
{
    int idx = blockIdx.x * 256 + threadIdx.x;   // NPIX*112, exact grid
    int cp = idx % 112;
    int pix = idx / 112;
    int b = pix / HW_;
    int hw = pix % HW_;
    int c = cp * 2;
    float v0 = 0.f, v1 = 0.f;
    const float* src = nullptr; int sc = 0, nc = 0;
    if (c < 64)       { src = cfw;  sc = c;       nc = 64; }
    else if (c < 128) { src = fpro; sc = c - 64;  nc = 64; }
    else if (c < 192) { src = fprv; sc = c - 128; nc = 64; }
    else if (c < 194) { src = f1;   sc = c - 192; nc = 2;  }
    else if (c < 196) { src = f2;   sc = c - 194; nc = 2;  }
    if (src) {
        v0 = src[((size_t)b * nc + sc    ) * HW_ + hw];
        v1 = src[((size_t)b * nc + sc + 1) * HW_ + hw];
    }
    X1p[idx] = (unsigned int)f2bf(v0) | ((unsigned int)f2bf(v1) << 16);
}

// ---------------------------------------------------------------------------
// Prep 1b: grouped planar sampling buffer Xg[g][NPIX][8] bf16 from cfw (NCHW).
// Run AFTER conv4 (into dead buf1). 16 B/pixel rows -> dense gather lines.
// ---------------------------------------------------------------------------
__global__ __launch_bounds__(256) void prep_xg(
    const float* __restrict__ cfw, unsigned short* __restrict__ Xg)
{
    int idx = blockIdx.x * 256 + threadIdx.x;   // 8*NPIX, exact grid
    int g = idx / NPIX;
    int pix = idx - g * NPIX;
    int b = pix / HW_;
    int hw = pix - b * HW_;
    const float* src = cfw + ((size_t)b * 64 + g * 8) * HW_ + hw;
    uint4 o;
    o.x = cvt_pk_bf16(src[0],            src[(size_t)HW_]);
    o.y = cvt_pk_bf16(src[2*(size_t)HW_], src[3*(size_t)HW_]);
    o.z = cvt_pk_bf16(src[4*(size_t)HW_], src[5*(size_t)HW_]);
    o.w = cvt_pk_bf16(src[6*(size_t)HW_], src[7*(size_t)HW_]);
    *(uint4*)(Xg + (size_t)idx * 8) = o;
}

// ---------------------------------------------------------------------------
// Prep 2: pack conv weights (OIHW fp32) -> MFMA B-frag order bf16.
// Bt[t][ck][nf][lane][8]; n = nf*16+(lane&15), k = ck*32+(lane>>4)*8+j (input ch)
// ---------------------------------------------------------------------------
__global__ __launch_bounds__(256) void prep_w(
    const float* __restrict__ w, unsigned short* __restrict__ Bt,
    int Cin, int KCH, int Nout, int NFTOT)
{
    int idx = blockIdx.x * 256 + threadIdx.x;
    int total = 9 * KCH * NFTOT * 64;
    if (idx >= total) return;
    int lane = idx & 63;
    int r = idx >> 6;
    int nf = r % NFTOT; r /= NFTOT;
    int ck = r % KCH;
    int t  = r / KCH;
    int n  = nf * 16 + (lane & 15);
    int kb = ck * 32 + (lane >> 4) * 8;
    short8 o;
    #pragma unroll
    for (int j = 0; j < 8; ++j) {
        int c = kb + j;
        float v = (c < Cin && n < Nout) ? w[((size_t)n * Cin + c) * 9 + t] : 0.f;
        o[j] = (short)f2bf(v);
    }
    *(short8*)(Bt + (size_t)idx * 8) = o;
}

// ---------------------------------------------------------------------------
// Prep 3: pack deform weights. Btd[g][ck(3)][nf(4)][lane][8];
// k (within group, 0..95) = t*8 + c ; weight = wdef[oc][g*8+c][t], t>=9 -> 0
// ---------------------------------------------------------------------------
__global__ __launch_bounds__(256) void prep_wd(
    const float* __restrict__ w, unsigned short* __restrict__ Btd)
{
    int idx = blockIdx.x * 256 + threadIdx.x;   // 8*3*4*64 = 6144
    if (idx >= 8 * 3 * 4 * 64) return;
    int lane = idx & 63;
    int r = idx >> 6;
    int nf = r % 4; r >>= 2;
    int ck = r % 3;
    int g  = r / 3;
    int n  = nf * 16 + (lane & 15);             // oc
    int kb = ck * 32 + (lane >> 4) * 8;
    short8 o;
    #pragma unroll
    for (int j = 0; j < 8; ++j) {
        int k = kb + j;
        int t = k >> 3, c = k & 7;
        float v = (t < 9) ? w[((size_t)n * 64 + g * 8 + c) * 9 + t] : 0.f;
        o[j] = (short)f2bf(v);
    }
    *(short8*)(Btd + (size_t)idx * 8) = o;
}

// ---------------------------------------------------------------------------
// MFMA implicit-GEMM 3x3 conv, pad=1. X: NHWC bf16 (C = KCH*32).
// MODE 0: store bf16 NHWC (optional lrelu).
// MODE 1 (conv4): fold flow-add (oc<144) / sigmoid (oc>=144), store grouped
//                 o4g[g][NPIX][28] bf16: [t*2+d] = offset, [18+t] = mask.
// ---------------------------------------------------------------------------
template<int KCH, int NFTOT, int NF, bool RELU, int MODE>
__global__ __launch_bounds__(256) void conv_mfma(
    const unsigned short* __restrict__ X, const unsigned short* __restrict__ Bt,
    const float* __restrict__ bias, unsigned short* __restrict__ Y,
    int CoutTot, int fBase0,
    const float* __restrict__ f1, const float* __restrict__ f2)
{
    constexpr int CPAD = KCH * 32;
    const int lane = threadIdx.x & 63;
    const int wv   = threadIdx.x >> 6;
    const int m0   = blockIdx.x * 128 + wv * 32;
    const int fBase = fBase0 + blockIdx.y * NF;
    const int lm = lane & 15;
    const int kj = (lane >> 4) * 8;

    int p[2], hh[2], wp[2];
    #pragma unroll
    for (int mf = 0; mf < 2; ++mf) {
        int pm = m0 + mf * 16 + lm;
        p[mf] = pm;
        hh[mf] = (pm / W_) % H_;
        wp[mf] = pm % W_;
    }

    f32x4 acc[2][NF];
    #pragma unroll
    for (int nf = 0; nf < NF; ++nf) {
        int oc = (fBase + nf) * 16 + lm;
        float bv = (oc < CoutTot) ? bias[oc] : 0.f;
        f32x4 a = {bv, bv, bv, bv};
        acc[0][nf] = a; acc[1][nf] = a;
    }

    const short8 zero = {0,0,0,0,0,0,0,0};

    #pragma unroll
    for (int ck = 0; ck < KCH; ++ck) {
        const int c0 = ck * 32;
        #pragma unroll
        for (int t = 0; t < 9; ++t) {
            const int di = t / 3 - 1, dj = t % 3 - 1;
            const unsigned short* bp =
                Bt + (((size_t)(t * KCH + ck) * NFTOT + fBase) * 64 + lane) * 8;
            short8 bfr[NF];
            #pragma unroll
            for (int nf = 0; nf < NF; ++nf)
                bfr[nf] = *(const short8*)(bp + (size_t)nf * 512);
            #pragma unroll
            for (int mf = 0; mf < 2; ++mf) {
                bool val = ((unsigned)(hh[mf] + di) < (unsigned)H_) &&
                           ((unsigned)(wp[mf] + dj) < (unsigned)W_);
                const unsigned short* ap =
                    X + (size_t)(p[mf] + di * W_ + dj) * CPAD + c0 + kj;
                short8 afr = val ? *(const short8*)ap : zero;
                #pragma unroll
                for (int nf = 0; nf < NF; ++nf)
                    acc[mf][nf] = __builtin_amdgcn_mfma_f32_16x16x32_bf16(
                        afr, bfr[nf], acc[mf][nf], 0, 0, 0);
            }
        }
    }

    const int prow = (lane >> 4) * 4;
    #pragma unroll
    for (int mf = 0; mf < 2; ++mf)
        #pragma unroll
        for (int nf = 0; nf < NF; ++nf) {
            int oc = (fBase + nf) * 16 + lm;
            if (oc < CoutTot) {
                #pragma unroll
                for (int r = 0; r < 4; ++r) {
                    int pix = m0 + mf * 16 + prow + r;
                    float v = acc[mf][nf][r];
                    if (MODE == 0) {
                        if (RELU) v = (v >= 0.f) ? v : 0.1f * v;
                        Y[(size_t)pix * CoutTot + oc] = f2bf(v);
                    } else {
                        int bb = pix / HW_, hw = pix % HW_;
                        if (oc < 144) {
                            int pr = oc >> 1, d = oc & 1;
                            int g = pr / 9, t = pr - g * 9;
                            const float* fl = (g < 4) ? f1 : f2;
                            v += fl[((size_t)bb * 2 + (d ^ 1)) * HW_ + hw];
                            Y[((size_t)g * NPIX + pix) * 28 + t * 2 + d] = f2bf(v);
                        } else {
                            int mi = oc - 144;
                            int g = mi / 9, t = mi - g * 9;
                            v = 1.f / (1.f + expf(-v));
                            Y[((size_t)g * NPIX + pix) * 28 + 18 + t] = f2bf(v);
                        }
                    }
                }
            }
        }
}

// ---------------------------------------------------------------------------
// Fused deformable conv: sample (from grouped planes) -> LDS (XOR-swizzled)
// -> MFMA. Block = 128 pixels, 256 threads (4 waves, wave = 32 pix x 64 oc).
// LDS samp: [128 pix][16 slots][8 bf16] (256 B/row), slot = t ^ (pix&7).
// K per group = 96 (taps 0..8 -> cols t*8..t*8+8, cols 72..95 stay zero).
// ---------------------------------------------------------------------------
__global__ __launch_bounds__(256) void deform_mfma(
    const unsigned short* __restrict__ Xg,   // [8][NPIX][8] bf16 planes
    const unsigned short* __restrict__ o4g,  // [8][NPIX][28] bf16
    const unsigned short* __restrict__ Btd,  // [8][3][4][64][8] bf16
    const float* __restrict__ bia,           // 64
    float* __restrict__ out)                 // B,64,H,W fp32 NCHW
{
    __shared__ __align__(16) char lds[128 * 65 * 4];   // 33280 B
    float* sout = (float*)lds;                         // [128][65]

    const int tid  = threadIdx.x;
    const int lane = tid & 63;
    const int wv   = tid >> 6;
    const int lm   = lane & 15;
    const int pix0 = blockIdx.x * 128;
    const int b    = pix0 / HW_;
    const int hw0  = pix0 % HW_;

    // zero samp region once (slots never written stay zero across all groups)
    {
        uint4 z = {0u, 0u, 0u, 0u};
        #pragma unroll
        for (int i = 0; i < 8; ++i)
            ((uint4*)lds)[i * 256 + tid] = z;
    }

    f32x4 acc[2][4];
    #pragma unroll
    for (int nf = 0; nf < 4; ++nf) {
        float bv = bia[nf * 16 + lm];
        f32x4 a = {bv, bv, bv, bv};
        acc[0][nf] = a; acc[1][nf] = a;
    }

    for (int g = 0; g < 8; ++g) {
        const unsigned short* Xp = Xg + (size_t)g * NPIX * 8;
        __syncthreads();   // prev group's MFMA reads done (also covers zero-init)

        // ---- phase A: prefetch offsets/masks for all 5 units (independent) ----
        unsigned int ddv[5];
        float mval[5];
        #pragma unroll
        for (int it = 0; it < 5; ++it) {
            int u = it * 256 + tid;
            bool act = (it < 4) || (tid < 128);
            if (act) {
                int t   = u >> 7;
                int pix = u & 127;
                size_t ob = ((size_t)g * NPIX + pix0 + pix) * 28;
                ddv[it]  = *(const unsigned int*)(o4g + ob + t * 2);
                mval[it] = bf2f(o4g[ob + 18 + t]);
            }
        }
        // ---- phase B: gather + bilinear + pack + LDS write, per unit ----
        #pragma unroll
        for (int it = 0; it < 5; ++it) {
            int u = it * 256 + tid;
            bool act = (it < 4) || (tid < 128);
            if (act) {
                int t   = u >> 7;
                int pix = u & 127;
                int hw = hw0 + pix;
                int h = hw / W_;
                int w = hw - h * W_;
                float dy = bf2f((unsigned short)(ddv[it] & 0xFFFFu));
                float dx = bf2f((unsigned short)(ddv[it] >> 16));
                float m  = mval[it];

                float ys = dy + (float)(h - 1 + t / 3);
                float xs = dx + (float)(w - 1 + t % 3);
                float y0f = floorf(ys), x0f = floorf(xs);
                float wy1 = ys - y0f, wx1 = xs - x0f;
                float wy0 = 1.f - wy1, wx0 = 1.f - wx1;
                int iy0 = (int)y0f, ix0 = (int)x0f;
                int iy1 = iy0 + 1,  ix1 = ix0 + 1;
                bool vy0 = (unsigned)iy0 < (unsigned)H_;
                bool vy1 = (unsigned)iy1 < (unsigned)H_;
                bool vx0 = (unsigned)ix0 < (unsigned)W_;
                bool vx1 = (unsigned)ix1 < (unsigned)W_;
                int cy0 = min(max(iy0, 0), H_ - 1), cy1 = min(max(iy1, 0), H_ - 1);
                int cx0 = min(max(ix0, 0), W_ - 1), cx1 = min(max(ix1, 0), W_ - 1);
                float w00 = (vy0 && vx0) ? wy0 * wx0 * m : 0.f;
                float w01 = (vy0 && vx1) ? wy0 * wx1 * m : 0.f;
                float w10 = (vy1 && vx0) ? wy1 * wx0 * m : 0.f;
                float w11 = (vy1 && vx1) ? wy1 * wx1 * m : 0.f;

                size_t r0 = (size_t)b * HW_ + (size_t)cy0 * W_;
                size_t r1 = (size_t)b * HW_ + (size_t)cy1 * W_;
                uint4 c00 = *(const uint4*)(Xp + (r0 + cx0) * 8);
                uint4 c01 = *(const uint4*)(Xp + (r0 + cx1) * 8);
                uint4 c10 = *(const uint4*)(Xp + (r1 + cx0) * 8);
                uint4 c11 = *(const uint4*)(Xp + (r1 + cx1) * 8);

                float a8[8];
                #pragma unroll
                for (int i = 0; i < 8; ++i) a8[i] = 0.f;
                const unsigned int u00[4] = {c00.x, c00.y, c00.z, c00.w};
                const unsigned int u01[4] = {c01.x, c01.y, c01.z, c01.w};
                const unsigned int u10[4] = {c10.x, c10.y, c10.z, c10.w};
                const unsigned int u11[4] = {c11.x, c11.y, c11.z, c11.w};
                #pragma unroll
                for (int i = 0; i < 4; ++i) {
                    a8[2*i]   += w00 * __builtin_bit_cast(float, u00[i] << 16);
                    a8[2*i+1] += w00 * __builtin_bit_cast(float, u00[i] & 0xFFFF0000u);
                    a8[2*i]   += w01 * __builtin_bit_cast(float, u01[i] << 16);
                    a8[2*i+1] += w01 * __builtin_bit_cast(float, u01[i] & 0xFFFF0000u);
                    a8[2*i]   += w10 * __builtin_bit_cast(float, u10[i] << 16);
                    a8[2*i+1] += w10 * __builtin_bit_cast(float, u10[i] & 0xFFFF0000u);
                    a8[2*i]   += w11 * __builtin_bit_cast(float, u11[i] << 16);
                    a8[2*i+1] += w11 * __builtin_bit_cast(float, u11[i] & 0xFFFF0000u);
                }
                uint4 ov;
                ov.x = cvt_pk_bf16(a8[0], a8[1]);
                ov.y = cvt_pk_bf16(a8[2], a8[3]);
                ov.z = cvt_pk_bf16(a8[4], a8[5]);
                ov.w = cvt_pk_bf16(a8[6], a8[7]);
                int slot = t ^ (pix & 7);
                *(uint4*)(lds + pix * 256 + slot * 16) = ov;
            }
        }
        __syncthreads();
        // ---- MFMA: K=96 over this group ----
        #pragma unroll
        for (int ck = 0; ck < 3; ++ck) {
            const short8* bpp = (const short8*)Btd + ((size_t)(g * 3 + ck) * 4) * 64 + lane;
            short8 bfr[4];
            #pragma unroll
            for (int nf = 0; nf < 4; ++nf) bfr[nf] = bpp[nf * 64];
            const int slotbase = ck * 4 + (lane >> 4);
            #pragma unroll
            for (int mf = 0; mf < 2; ++mf) {
                int row = wv * 32 + mf * 16 + lm;
                int slot = slotbase ^ (lm & 7);
                short8 afr = *(const short8*)(lds + row * 256 + slot * 16);
                #pragma unroll
                for (int nf = 0; nf < 4; ++nf)
                    acc[mf][nf] = __builtin_amdgcn_mfma_f32_16x16x32_bf16(
                        afr, bfr[nf], acc[mf][nf], 0, 0, 0);
            }
        }
    }

    // ---- epilogue: restage through LDS for coalesced NCHW stores ----
    __syncthreads();
    const int prow = (lane >> 4) * 4;
    #pragma unroll
    for (int mf = 0; mf < 2; ++mf)
        #pragma unroll
        for (int nf = 0; nf < 4; ++nf)
            #pragma unroll
            for (int r = 0; r < 4; ++r)
                sout[(wv * 32 + mf * 16 + prow + r) * 65 + nf * 16 + lm] = acc[mf][nf][r];
    __syncthreads();
    #pragma unroll
    for (int i = 0; i < 32; ++i) {
        int idx = i * 256 + tid;        // 8192 = 128 pix x 64 oc
        int oc = idx >> 7;
        int pp = idx & 127;
        out[((size_t)(b * 64 + oc)) * HW_ + hw0 + pp] = sout[pp * 65 + oc];
    }
}

// ---------------------------------------------------------------------------
extern "C" void kernel_launch(void* const* d_in, const int* in_sizes, int n_in,
                              void* d_out, int out_size, void* d_ws, size_t ws_size,
                              hipStream_t stream)
{
    const float* cfw  = (const float*)d_in[0];
    const float* fpro = (const float*)d_in[1];
    const float* fprv = (const float*)d_in[2];
    const float* fl1  = (const float*)d_in[3];
    const float* fl2  = (const float*)d_in[4];
    const float* w1   = (const float*)d_in[5];
    const float* b1   = (const float*)d_in[6];
    const float* w2   = (const float*)d_in[7];
    const float* b2   = (const float*)d_in[8];
    const float* w3   = (const float*)d_in[9];
    const float* b3   = (const float*)d_in[10];
    const float* w4   = (const float*)d_in[11];
    const float* b4   = (const float*)d_in[12];
    const float* wdef = (const float*)d_in[13];
    const float* bdef = (const float*)d_in[14];
    float* out = (float*)d_out;

    // ---- workspace layout (bytes) ----
    // [0, 55,050,240)               X1 [NPIX][224] bf16 (live until conv1)
    // [55,050,240, 70,778,880)      buf1: o1, then o3, then Xg [8][NPIX][8]
    // [70,778,880, 125,829,120)     o4g [8][NPIX][28] bf16; o2 at its start
    // [125,829,120, ~126.6 MB)      packed weights
    char* ws = (char*)d_ws;
    unsigned short* X1  = (unsigned short*)(ws);
    unsigned short* buf1= (unsigned short*)(ws + 55050240);   // o1 / o3 / Xg
    unsigned short* o2  = (unsigned short*)(ws + 70778880);   // dead after conv3
    unsigned short* o4g = (unsigned short*)(ws + 70778880);   // clobbers o2 (OK)
    unsigned short* Bt1 = (unsigned short*)(ws + 125829120);
    unsigned short* Bt2 = (unsigned short*)(ws + 125829120 + 258048);
    unsigned short* Bt3 = (unsigned short*)(ws + 125829120 + 258048 + 73728);
    unsigned short* Bt4 = (unsigned short*)(ws + 125829120 + 258048 + 2*73728);
    unsigned short* Btd = (unsigned short*)(ws + 125829120 + 2*258048 + 2*73728);

    prep_x1<<<dim3((NPIX * 112) / 256), dim3(256), 0, stream>>>(
        cfw, fpro, fprv, fl1, fl2, (unsigned int*)X1);
    prep_w<<<dim3((9*7*4*64 + 255) / 256), dim3(256), 0, stream>>>(w1, Bt1, 196, 7, 64, 4);
    prep_w<<<dim3((9*2*4*64 + 255) / 256), dim3(256), 0, stream>>>(w2, Bt2, 64, 2, 64, 4);
    prep_w<<<dim3((9*2*4*64 + 255) / 256), dim3(256), 0, stream>>>(w3, Bt3, 64, 2, 64, 4);
    prep_w<<<dim3((9*2*14*64 + 255) / 256), dim3(256), 0, stream>>>(w4, Bt4, 64, 2, 216, 14);
    prep_wd<<<dim3((8*3*4*64 + 255) / 256), dim3(256), 0, stream>>>(wdef, Btd);

    dim3 blk(256);
    dim3 gridM(NPIX / 128, 1);
    // conv1: X1(196) -> o1 (buf1), lrelu
    conv_mfma<7, 4, 4, true, 0><<<gridM, blk, 0, stream>>>(X1, Bt1, b1, buf1, 64, 0, nullptr, nullptr);
    // conv2: o1 (buf1) -> o2, lrelu
    conv_mfma<2, 4, 4, true, 0><<<gridM, blk, 0, stream>>>(buf1, Bt2, b2, o2, 64, 0, nullptr, nullptr);
    // conv3: o2 -> o3 (buf1, o1 dead), lrelu
    conv_mfma<2, 4, 4, true, 0><<<gridM, blk, 0, stream>>>(o2, Bt3, b3, buf1, 64, 0, nullptr, nullptr);
    // conv4: o3 (buf1) -> o4g (clobbers o2, dead) with flow-add/sigmoid epilogue
    conv_mfma<2, 14, 4, false, 1><<<dim3(NPIX / 128, 3), blk, 0, stream>>>(buf1, Bt4, b4, o4g, 216, 0, fl1, fl2);
    conv_mfma<2, 14, 2, false, 1><<<dim3(NPIX / 128, 1), blk, 0, stream>>>(buf1, Bt4, b4, o4g, 216, 12, fl1, fl2);
    // grouped planar sampling buffer (into buf1; o3 dead after conv4)
    prep_xg<<<dim3((8 * NPIX) / 256), dim3(256), 0, stream>>>(cfw, buf1);
    // fused deformable conv
    deform_mfma<<<dim3(NPIX / 128), blk, 0, stream>>>(buf1, o4g, Btd, bdef, out);
}

// Round 5
// 322.228 us; speedup vs baseline: 5.8268x; 1.5385x over previous
//
#include <hip/hip_runtime.h>
#include <hip/hip_bf16.h>
#include <math.h>

typedef __attribute__((ext_vector_type(8))) short short8;
typedef __attribute__((ext_vector_type(4))) float f32x4;

constexpr int B_ = 8, H_ = 96, W_ = 160;
constexpr int HW_ = H_ * W_;
constexpr int NPIX = B_ * HW_;        // 122880

__device__ __forceinline__ unsigned short f2bf(float f) {
    unsigned int u = __builtin_bit_cast(unsigned int, f);
    u += 0x7FFFu + ((u >> 16) & 1u);          // RNE
    return (unsigned short)(u >> 16);
}
__device__ __forceinline__ float bf2f(unsigned short s) {
    unsigned int u = ((unsigned int)s) << 16;
    return __builtin_bit_cast(float, u);
}
__device__ __forceinline__ unsigned int cvt_pk_bf16(float lo, float hi) {
    unsigned int r;
    asm volatile("v_cvt_pk_bf16_f32 %0, %1, %2" : "=v"(r) : "v"(lo), "v"(hi));
    return r;   // D[15:0]=bf16(lo), D[31:16]=bf16(hi)
}
__device__ __forceinline__ float f4get(const float4& v, int q) {
    switch (q) { case 0: return v.x; case 1: return v.y;
                 case 2: return v.z; default: return v.w; }
}

// ---------------------------------------------------------------------------
// Prep 1: concat inputs -> octet-planar bf16 X1[c8][NPIX][8], c8 = 0..27.
// Channels: 0..63 cfw, 64..127 fpro, 128..191 fprv, 192/193 f1, 194/195 f2,
// 196..223 zero. Each thread: 4 contiguous pixels x 8 channels.
// Reads: float4, fully coalesced. Writes: 4x16B per lane, wave covers 4KB.
// ---------------------------------------------------------------------------
__global__ __launch_bounds__(256) void prep_x1(
    const float* __restrict__ cfw, const float* __restrict__ fpro,
    const float* __restrict__ fprv, const float* __restrict__ f1,
    const float* __restrict__ f2, unsigned short* __restrict__ X1)
{
    const int c8 = blockIdx.y;
    const int pix0 = blockIdx.x * 1024 + threadIdx.x * 4;   // grid.x = NPIX/1024
    unsigned short* dst = X1 + ((size_t)c8 * NPIX + pix0) * 8;

    if (c8 >= 25) {   // channels 200..223 are all zero
        uint4 z = {0u, 0u, 0u, 0u};
        #pragma unroll
        for (int q = 0; q < 4; ++q) *(uint4*)(dst + q * 8) = z;
        return;
    }

    const int b  = pix0 / HW_;          // 1024 | HW_, no batch crossing
    const int hw = pix0 - b * HW_;

    float4 v[8];
    #pragma unroll
    for (int j = 0; j < 8; ++j) {
        int c = c8 * 8 + j;
        const float* src = nullptr; int sc = 0, nc = 0;
        if (c < 64)       { src = cfw;  sc = c;       nc = 64; }
        else if (c < 128) { src = fpro; sc = c - 64;  nc = 64; }
        else if (c < 192) { src = fprv; sc = c - 128; nc = 64; }
        else if (c < 194) { src = f1;   sc = c - 192; nc = 2;  }
        else if (c < 196) { src = f2;   sc = c - 194; nc = 2;  }
        if (src) v[j] = *(const float4*)(src + ((size_t)b * nc + sc) * HW_ + hw);
        else     { v[j].x = v[j].y = v[j].z = v[j].w = 0.f; }
    }
    #pragma unroll
    for (int q = 0; q < 4; ++q) {
        uint4 o;
        o.x = cvt_pk_bf16(f4get(v[0], q), f4get(v[1], q));
        o.y = cvt_pk_bf16(f4get(v[2], q), f4get(v[3], q));
        o.z = cvt_pk_bf16(f4get(v[4], q), f4get(v[5], q));
        o.w = cvt_pk_bf16(f4get(v[6], q), f4get(v[7], q));
        *(uint4*)(dst + q * 8) = o;
    }
}

// ---------------------------------------------------------------------------
// Prep 2: pack conv weights (OIHW fp32) -> MFMA B-frag order bf16.
// Bt[t][ck][nf][lane][8]; n = nf*16+(lane&15), k = ck*32+(lane>>4)*8+j (input ch)
// ---------------------------------------------------------------------------
__global__ __launch_bounds__(256) void prep_w(
    const float* __restrict__ w, unsigned short* __restrict__ Bt,
    int Cin, int KCH, int Nout, int NFTOT)
{
    int idx = blockIdx.x * 256 + threadIdx.x;
    int total = 9 * KCH * NFTOT * 64;
    if (idx >= total) return;
    int lane = idx & 63;
    int r = idx >> 6;
    int nf = r % NFTOT; r /= NFTOT;
    int ck = r % KCH;
    int t  = r / KCH;
    int n  = nf * 16 + (lane & 15);
    int kb = ck * 32 + (lane >> 4) * 8;
    short8 o;
    #pragma unroll
    for (int j = 0; j < 8; ++j) {
        int c = kb + j;
        float v = (c < Cin && n < Nout) ? w[((size_t)n * Cin + c) * 9 + t] : 0.f;
        o[j] = (short)f2bf(v);
    }
    *(short8*)(Bt + (size_t)idx * 8) = o;
}

// ---------------------------------------------------------------------------
// Prep 3: pack deform weights. Btd[g][ck(3)][nf(4)][lane][8];
// k (within group, 0..95) = t*8 + c ; weight = wdef[oc][g*8+c][t], t>=9 -> 0
// ---------------------------------------------------------------------------
__global__ __launch_bounds__(256) void prep_wd(
    const float* __restrict__ w, unsigned short* __restrict__ Btd)
{
    int idx = blockIdx.x * 256 + threadIdx.x;   // 8*3*4*64 = 6144
    if (idx >= 8 * 3 * 4 * 64) return;
    int lane = idx & 63;
    int r = idx >> 6;
    int nf = r % 4; r >>= 2;
    int ck = r % 3;
    int g  = r / 3;
    int n  = nf * 16 + (lane & 15);             // oc
    int kb = ck * 32 + (lane >> 4) * 8;
    short8 o;
    #pragma unroll
    for (int j = 0; j < 8; ++j) {
        int k = kb + j;
        int t = k >> 3, c = k & 7;
        float v = (t < 9) ? w[((size_t)n * 64 + g * 8 + c) * 9 + t] : 0.f;
        o[j] = (short)f2bf(v);
    }
    *(short8*)(Btd + (size_t)idx * 8) = o;
}

// ---------------------------------------------------------------------------
// MFMA implicit-GEMM 3x3 conv, pad=1. X: octet-planar bf16 [KCH*4][NPIX][8].
// MODE 0: store octet-planar bf16 (optional lrelu).
// MODE 1 (conv4): fold flow-add (oc<144) / sigmoid (oc>=144), store grouped
//                 o4g[g][NPIX][28] bf16: [t*2+d] = offset, [18+t] = mask.
// ---------------------------------------------------------------------------
template<int KCH, int NFTOT, int NF, bool RELU, int MODE>
__global__ __launch_bounds__(256) void conv_mfma(
    const unsigned short* __restrict__ X, const unsigned short* __restrict__ Bt,
    const float* __restrict__ bias, unsigned short* __restrict__ Y,
    int CoutTot, int fBase0,
    const float* __restrict__ f1, const float* __restrict__ f2)
{
    const int lane = threadIdx.x & 63;
    const int wv   = threadIdx.x >> 6;
    const int m0   = blockIdx.x * 128 + wv * 32;
    const int fBase = fBase0 + blockIdx.y * NF;
    const int lm = lane & 15;
    const int l16 = lane >> 4;

    int p[2], hh[2], wp[2];
    #pragma unroll
    for (int mf = 0; mf < 2; ++mf) {
        int pm = m0 + mf * 16 + lm;
        p[mf] = pm;
        hh[mf] = (pm / W_) % H_;
        wp[mf] = pm % W_;
    }

    f32x4 acc[2][NF];
    #pragma unroll
    for (int nf = 0; nf < NF; ++nf) {
        int oc = (fBase + nf) * 16 + lm;
        float bv = (oc < CoutTot) ? bias[oc] : 0.f;
        f32x4 a = {bv, bv, bv, bv};
        acc[0][nf] = a; acc[1][nf] = a;
    }

    const short8 zero = {0,0,0,0,0,0,0,0};

    #pragma unroll
    for (int ck = 0; ck < KCH; ++ck) {
        const int p8 = ck * 4 + l16;                     // octet plane
        const unsigned short* Xp = X + (size_t)p8 * NPIX * 8;
        #pragma unroll
        for (int t = 0; t < 9; ++t) {
            const int di = t / 3 - 1, dj = t % 3 - 1;
            const unsigned short* bp =
                Bt + (((size_t)(t * KCH + ck) * NFTOT + fBase) * 64 + lane) * 8;
            short8 bfr[NF];
            #pragma unroll
            for (int nf = 0; nf < NF; ++nf)
                bfr[nf] = *(const short8*)(bp + (size_t)nf * 512);
            #pragma unroll
            for (int mf = 0; mf < 2; ++mf) {
                bool val = ((unsigned)(hh[mf] + di) < (unsigned)H_) &&
                           ((unsigned)(wp[mf] + dj) < (unsigned)W_);
                const unsigned short* ap = Xp + (size_t)(p[mf] + di * W_ + dj) * 8;
                short8 afr = val ? *(const short8*)ap : zero;
                #pragma unroll
                for (int nf = 0; nf < NF; ++nf)
                    acc[mf][nf] = __builtin_amdgcn_mfma_f32_16x16x32_bf16(
                        afr, bfr[nf], acc[mf][nf], 0, 0, 0);
            }
        }
    }

    const int prow = l16 * 4;
    #pragma unroll
    for (int mf = 0; mf < 2; ++mf)
        #pragma unroll
        for (int nf = 0; nf < NF; ++nf) {
            int oc = (fBase + nf) * 16 + lm;
            if (oc < CoutTot) {
                #pragma unroll
                for (int r = 0; r < 4; ++r) {
                    int pix = m0 + mf * 16 + prow + r;
                    float v = acc[mf][nf][r];
                    if (MODE == 0) {
                        if (RELU) v = (v >= 0.f) ? v : 0.1f * v;
                        Y[((size_t)(oc >> 3) * NPIX + pix) * 8 + (oc & 7)] = f2bf(v);
                    } else {
                        int bb = pix / HW_, hw = pix % HW_;
                        if (oc < 144) {
                            int pr = oc >> 1, d = oc & 1;
                            int g = pr / 9, t = pr - g * 9;
                            const float* fl = (g < 4) ? f1 : f2;
                            v += fl[((size_t)bb * 2 + (d ^ 1)) * HW_ + hw];
                            Y[((size_t)g * NPIX + pix) * 28 + t * 2 + d] = f2bf(v);
                        } else {
                            int mi = oc - 144;
                            int g = mi / 9, t = mi - g * 9;
                            v = 1.f / (1.f + expf(-v));
                            Y[((size_t)g * NPIX + pix) * 28 + 18 + t] = f2bf(v);
                        }
                    }
                }
            }
        }
}

// ---------------------------------------------------------------------------
// Fused deformable conv: sample (from X1 octet planes 0..7 = cfw) -> LDS
// (XOR-swizzled) -> MFMA. Block = 128 pixels, 256 threads (4 waves).
// LDS samp: [128 pix][16 slots][8 bf16] (256 B/row), slot = t ^ (pix&7).
// K per group = 96 (taps 0..8 -> cols t*8..t*8+8, cols 72..95 stay zero).
// ---------------------------------------------------------------------------
__global__ __launch_bounds__(256) void deform_mfma(
    const unsigned short* __restrict__ Xg,   // [8][NPIX][8] bf16 planes (X1)
    const unsigned short* __restrict__ o4g,  // [8][NPIX][28] bf16
    const unsigned short* __restrict__ Btd,  // [8][3][4][64][8] bf16
    const float* __restrict__ bia,           // 64
    float* __restrict__ out)                 // B,64,H,W fp32 NCHW
{
    __shared__ __align__(16) char lds[128 * 65 * 4];   // 33280 B
    float* sout = (float*)lds;                         // [128][65]

    const int tid  = threadIdx.x;
    const int lane = tid & 63;
    const int wv   = tid >> 6;
    const int lm   = lane & 15;
    const int pix0 = blockIdx.x * 128;
    const int b    = pix0 / HW_;
    const int hw0  = pix0 % HW_;

    // zero samp region once (slots never written stay zero across all groups)
    {
        uint4 z = {0u, 0u, 0u, 0u};
        #pragma unroll
        for (int i = 0; i < 8; ++i)
            ((uint4*)lds)[i * 256 + tid] = z;
    }

    f32x4 acc[2][4];
    #pragma unroll
    for (int nf = 0; nf < 4; ++nf) {
        float bv = bia[nf * 16 + lm];
        f32x4 a = {bv, bv, bv, bv};
        acc[0][nf] = a; acc[1][nf] = a;
    }

    for (int g = 0; g < 8; ++g) {
        const unsigned short* Xp = Xg + (size_t)g * NPIX * 8;
        __syncthreads();   // prev group's MFMA reads done (also covers zero-init)

        // ---- phase A: prefetch offsets/masks for all 5 units (independent) ----
        unsigned int ddv[5];
        float mval[5];
        #pragma unroll
        for (int it = 0; it < 5; ++it) {
            int u = it * 256 + tid;
            bool act = (it < 4) || (tid < 128);
            if (act) {
                int t   = u >> 7;
                int pix = u & 127;
                size_t ob = ((size_t)g * NPIX + pix0 + pix) * 28;
                ddv[it]  = *(const unsigned int*)(o4g + ob + t * 2);
                mval[it] = bf2f(o4g[ob + 18 + t]);
            }
        }
        // ---- phase B: gather + bilinear + pack + LDS write, per unit ----
        #pragma unroll
        for (int it = 0; it < 5; ++it) {
            int u = it * 256 + tid;
            bool act = (it < 4) || (tid < 128);
            if (act) {
                int t   = u >> 7;
                int pix = u & 127;
                int hw = hw0 + pix;
                int h = hw / W_;
                int w = hw - h * W_;
                float dy = bf2f((unsigned short)(ddv[it] & 0xFFFFu));
                float dx = bf2f((unsigned short)(ddv[it] >> 16));
                float m  = mval[it];

                float ys = dy + (float)(h - 1 + t / 3);
                float xs = dx + (float)(w - 1 + t % 3);
                float y0f = floorf(ys), x0f = floorf(xs);
                float wy1 = ys - y0f, wx1 = xs - x0f;
                float wy0 = 1.f - wy1, wx0 = 1.f - wx1;
                int iy0 = (int)y0f, ix0 = (int)x0f;
                int iy1 = iy0 + 1,  ix1 = ix0 + 1;
                bool vy0 = (unsigned)iy0 < (unsigned)H_;
                bool vy1 = (unsigned)iy1 < (unsigned)H_;
                bool vx0 = (unsigned)ix0 < (unsigned)W_;
                bool vx1 = (unsigned)ix1 < (unsigned)W_;
                int cy0 = min(max(iy0, 0), H_ - 1), cy1 = min(max(iy1, 0), H_ - 1);
                int cx0 = min(max(ix0, 0), W_ - 1), cx1 = min(max(ix1, 0), W_ - 1);
                float w00 = (vy0 && vx0) ? wy0 * wx0 * m : 0.f;
                float w01 = (vy0 && vx1) ? wy0 * wx1 * m : 0.f;
                float w10 = (vy1 && vx0) ? wy1 * wx0 * m : 0.f;
                float w11 = (vy1 && vx1) ? wy1 * wx1 * m : 0.f;

                size_t r0 = (size_t)b * HW_ + (size_t)cy0 * W_;
                size_t r1 = (size_t)b * HW_ + (size_t)cy1 * W_;
                uint4 c00 = *(const uint4*)(Xp + (r0 + cx0) * 8);
                uint4 c01 = *(const uint4*)(Xp + (r0 + cx1) * 8);
                uint4 c10 = *(const uint4*)(Xp + (r1 + cx0) * 8);
                uint4 c11 = *(const uint4*)(Xp + (r1 + cx1) * 8);

                float a8[8];
                #pragma unroll
                for (int i = 0; i < 8; ++i) a8[i] = 0.f;
                const unsigned int u00[4] = {c00.x, c00.y, c00.z, c00.w};
                const unsigned int u01[4] = {c01.x, c01.y, c01.z, c01.w};
                const unsigned int u10[4] = {c10.x, c10.y, c10.z, c10.w};
                const unsigned int u11[4] = {c11.x, c11.y, c11.z, c11.w};
                #pragma unroll
                for (int i = 0; i < 4; ++i) {
                    a8[2*i]   += w00 * __builtin_bit_cast(float, u00[i] << 16);
                    a8[2*i+1] += w00 * __builtin_bit_cast(float, u00[i] & 0xFFFF0000u);
                    a8[2*i]   += w01 * __builtin_bit_cast(float, u01[i] << 16);
                    a8[2*i+1] += w01 * __builtin_bit_cast(float, u01[i] & 0xFFFF0000u);
                    a8[2*i]   += w10 * __builtin_bit_cast(float, u10[i] << 16);
                    a8[2*i+1] += w10 * __builtin_bit_cast(float, u10[i] & 0xFFFF0000u);
                    a8[2*i]   += w11 * __builtin_bit_cast(float, u11[i] << 16);
                    a8[2*i+1] += w11 * __builtin_bit_cast(float, u11[i] & 0xFFFF0000u);
                }
                uint4 ov;
                ov.x = cvt_pk_bf16(a8[0], a8[1]);
                ov.y = cvt_pk_bf16(a8[2], a8[3]);
                ov.z = cvt_pk_bf16(a8[4], a8[5]);
                ov.w = cvt_pk_bf16(a8[6], a8[7]);
                int slot = t ^ (pix & 7);
                *(uint4*)(lds + pix * 256 + slot * 16) = ov;
            }
        }
        __syncthreads();
        // ---- MFMA: K=96 over this group ----
        #pragma unroll
        for (int ck = 0; ck < 3; ++ck) {
            const short8* bpp = (const short8*)Btd + ((size_t)(g * 3 + ck) * 4) * 64 + lane;
            short8 bfr[4];
            #pragma unroll
            for (int nf = 0; nf < 4; ++nf) bfr[nf] = bpp[nf * 64];
            const int slotbase = ck * 4 + (lane >> 4);
            #pragma unroll
            for (int mf = 0; mf < 2; ++mf) {
                int row = wv * 32 + mf * 16 + lm;
                int slot = slotbase ^ (lm & 7);
                short8 afr = *(const short8*)(lds + row * 256 + slot * 16);
                #pragma unroll
                for (int nf = 0; nf < 4; ++nf)
                    acc[mf][nf] = __builtin_amdgcn_mfma_f32_16x16x32_bf16(
                        afr, bfr[nf], acc[mf][nf], 0, 0, 0);
            }
        }
    }

    // ---- epilogue: restage through LDS for coalesced NCHW stores ----
    __syncthreads();
    const int prow = (lane >> 4) * 4;
    #pragma unroll
    for (int mf = 0; mf < 2; ++mf)
        #pragma unroll
        for (int nf = 0; nf < 4; ++nf)
            #pragma unroll
            for (int r = 0; r < 4; ++r)
                sout[(wv * 32 + mf * 16 + prow + r) * 65 + nf * 16 + lm] = acc[mf][nf][r];
    __syncthreads();
    #pragma unroll
    for (int i = 0; i < 32; ++i) {
        int idx = i * 256 + tid;        // 8192 = 128 pix x 64 oc
        int oc = idx >> 7;
        int pp = idx & 127;
        out[((size_t)(b * 64 + oc)) * HW_ + hw0 + pp] = sout[pp * 65 + oc];
    }
}

// ---------------------------------------------------------------------------
extern "C" void kernel_launch(void* const* d_in, const int* in_sizes, int n_in,
                              void* d_out, int out_size, void* d_ws, size_t ws_size,
                              hipStream_t stream)
{
    const float* cfw  = (const float*)d_in[0];
    const float* fpro = (const float*)d_in[1];
    const float* fprv = (const float*)d_in[2];
    const float* fl1  = (const float*)d_in[3];
    const float* fl2  = (const float*)d_in[4];
    const float* w1   = (const float*)d_in[5];
    const float* b1   = (const float*)d_in[6];
    const float* w2   = (const float*)d_in[7];
    const float* b2   = (const float*)d_in[8];
    const float* w3   = (const float*)d_in[9];
    const float* b3   = (const float*)d_in[10];
    const float* w4   = (const float*)d_in[11];
    const float* b4   = (const float*)d_in[12];
    const float* wdef = (const float*)d_in[13];
    const float* bdef = (const float*)d_in[14];
    float* out = (float*)d_out;

    // ---- workspace layout (bytes) ----
    // [0, 55,050,240)               X1 [28][NPIX][8] bf16 (live until deform;
    //                               planes 0..7 = cfw, reused by deform)
    // [55,050,240, 70,778,880)      buf1 [8][NPIX][8]: o1, then o3
    // [70,778,880, 125,829,120)     o4g [8][NPIX][28] bf16; o2 at its start
    // [125,829,120, ~126.6 MB)      packed weights
    char* ws = (char*)d_ws;
    unsigned short* X1  = (unsigned short*)(ws);
    unsigned short* buf1= (unsigned short*)(ws + 55050240);   // o1 / o3
    unsigned short* o2  = (unsigned short*)(ws + 70778880);   // dead after conv3
    unsigned short* o4g = (unsigned short*)(ws + 70778880);   // clobbers o2 (OK)
    unsigned short* Bt1 = (unsigned short*)(ws + 125829120);
    unsigned short* Bt2 = (unsigned short*)(ws + 125829120 + 258048);
    unsigned short* Bt3 = (unsigned short*)(ws + 125829120 + 258048 + 73728);
    unsigned short* Bt4 = (unsigned short*)(ws + 125829120 + 258048 + 2*73728);
    unsigned short* Btd = (unsigned short*)(ws + 125829120 + 2*258048 + 2*73728);

    prep_x1<<<dim3(NPIX / 1024, 28), dim3(256), 0, stream>>>(
        cfw, fpro, fprv, fl1, fl2, X1);
    prep_w<<<dim3((9*7*4*64 + 255) / 256), dim3(256), 0, stream>>>(w1, Bt1, 196, 7, 64, 4);
    prep_w<<<dim3((9*2*4*64 + 255) / 256), dim3(256), 0, stream>>>(w2, Bt2, 64, 2, 64, 4);
    prep_w<<<dim3((9*2*4*64 + 255) / 256), dim3(256), 0, stream>>>(w3, Bt3, 64, 2, 64, 4);
    prep_w<<<dim3((9*2*14*64 + 255) / 256), dim3(256), 0, stream>>>(w4, Bt4, 64, 2, 216, 14);
    prep_wd<<<dim3((8*3*4*64 + 255) / 256), dim3(256), 0, stream>>>(wdef, Btd);

    dim3 blk(256);
    dim3 gridM(NPIX / 128, 1);
    // conv1: X1(196) -> o1 (buf1), lrelu
    conv_mfma<7, 4, 4, true, 0><<<gridM, blk, 0, stream>>>(X1, Bt1, b1, buf1, 64, 0, nullptr, nullptr);
    // conv2: o1 (buf1) -> o2, lrelu
    conv_mfma<2, 4, 4, true, 0><<<gridM, blk, 0, stream>>>(buf1, Bt2, b2, o2, 64, 0, nullptr, nullptr);
    // conv3: o2 -> o3 (buf1, o1 dead), lrelu
    conv_mfma<2, 4, 4, true, 0><<<gridM, blk, 0, stream>>>(o2, Bt3, b3, buf1, 64, 0, nullptr, nullptr);
    // conv4: o3 (buf1) -> o4g (clobbers o2, dead) with flow-add/sigmoid epilogue
    conv_mfma<2, 14, 4, false, 1><<<dim3(NPIX / 128, 3), blk, 0, stream>>>(buf1, Bt4, b4, o4g, 216, 0, fl1, fl2);
    conv_mfma<2, 14, 2, false, 1><<<dim3(NPIX / 128, 1), blk, 0, stream>>>(buf1, Bt4, b4, o4g, 216, 12, fl1, fl2);
    // fused deformable conv (samples X1 planes 0..7 = cfw)
    deform_mfma<<<dim3(NPIX / 128), blk, 0, stream>>>(X1, o4g, Btd, bdef, out);
}